// Round 11
// baseline (649.512 us; speedup 1.0000x reference)
//
#include <hip/hip_runtime.h>

// ---- problem constants ----
#define DIMQ 2048
#define NHQ  16
#define HDQ  128
#define BQ   2
#define SQ   2048
#define HIDQ 5632
#define MQ   (BQ * SQ)   // 4096
#define SC_ATTN 0.08838834764831845f  // 1/sqrt(128)

using u16 = unsigned short;
using u32 = unsigned int;
typedef __attribute__((ext_vector_type(8))) short s16x8;
typedef __attribute__((ext_vector_type(4))) float f32x4;

__device__ __forceinline__ float bf2f(u16 v) {
  union { u32 u; float f; } w; w.u = ((u32)v) << 16; return w.f;
}
__device__ __forceinline__ u16 f2bf(float f) {
  union { float f; u32 u; } w; w.f = f;
  u32 r = w.u + 0x7FFFu + ((w.u >> 16) & 1u);  // RNE
  return (u16)(r >> 16);
}

__device__ __forceinline__ f32x4 mfma16(s16x8 a, s16x8 b, f32x4 c) {
  return __builtin_amdgcn_mfma_f32_16x16x32_bf16(a, b, c, 0, 0, 0);
}

// async global->LDS, 16B per lane; LDS dest is wave-uniform base + lane*16
__device__ __forceinline__ void gl_lds16(const void* g, void* l) {
  __builtin_amdgcn_global_load_lds((const __attribute__((address_space(1))) void*)g,
                                   (__attribute__((address_space(3))) void*)l,
                                   16, 0, 0);
}

#define SBAR()                                   \
  {                                              \
    asm volatile("" ::: "memory");               \
    __builtin_amdgcn_s_barrier();                \
    asm volatile("" ::: "memory");               \
  }
#define LGKM0() asm volatile("s_waitcnt lgkmcnt(0)" ::: "memory")

// ---- weight transpose + fp32->bf16 convert: src[R][Cn] f32 -> dst[Cn][R] bf16 ----
__global__ __launch_bounds__(256) void transpose_cvt(const float* __restrict__ src,
                                                     u16* __restrict__ dst,
                                                     int R, int Cn) {
  __shared__ float tile[32][33];
  const int tx = threadIdx.x, ty = threadIdx.y;
  const int c0 = blockIdx.x * 32, r0 = blockIdx.y * 32;
#pragma unroll
  for (int i = 0; i < 4; ++i)
    tile[ty + i * 8][tx] = src[(size_t)(r0 + ty + i * 8) * Cn + c0 + tx];
  __syncthreads();
#pragma unroll
  for (int i = 0; i < 4; ++i)
    dst[(size_t)(c0 + ty + i * 8) * R + r0 + tx] = f2bf(tile[tx][ty + i * 8]);
}

// ---- FFN weight transpose with gate/up interleave: src[2048][5632] f32 ->
// dst row' = (n>>7)*256 + base + (n&127). ----
__global__ __launch_bounds__(256) void transpose_cvt_ffn(const float* __restrict__ src,
                                                         u16* __restrict__ dst,
                                                         int base) {
  __shared__ float tile[32][33];
  const int tx = threadIdx.x, ty = threadIdx.y;
  const int c0 = blockIdx.x * 32, r0 = blockIdx.y * 32;  // c0 over 5632, r0 over 2048
#pragma unroll
  for (int i = 0; i < 4; ++i)
    tile[ty + i * 8][tx] = src[(size_t)(r0 + ty + i * 8) * HIDQ + c0 + tx];
  __syncthreads();
#pragma unroll
  for (int i = 0; i < 4; ++i) {
    const int n = c0 + ty + i * 8;
    const int row = (n >> 7) * 256 + base + (n & 127);
    dst[(size_t)row * DIMQ + r0 + tx] = f2bf(tile[tx][ty + i * 8]);
  }
}

// ---- V transpose: qkv v-slice [s][d] bf16 -> Vt[bh][d][s] bf16 ----
__global__ __launch_bounds__(256) void vtrans_k(const u16* __restrict__ qkv,
                                                u16* __restrict__ vt) {
  __shared__ u16 tile[32][33];
  const int bh = blockIdx.z;
  const int b = bh >> 4, h = bh & 15;
  const int s0 = blockIdx.x * 32, d0 = blockIdx.y * 32;
  const int tx = threadIdx.x, ty = threadIdx.y;
  const u16* src = qkv + (size_t)(b * SQ) * 6144 + 4096 + h * HDQ;
#pragma unroll
  for (int i = 0; i < 4; ++i)
    tile[ty + i * 8][tx] = src[(size_t)(s0 + ty + i * 8) * 6144 + d0 + tx];
  __syncthreads();
  u16* dst = vt + (size_t)bh * HDQ * SQ;
#pragma unroll
  for (int i = 0; i < 4; ++i)
    dst[(size_t)(d0 + ty + i * 8) * SQ + s0 + tx] = tile[tx][ty + i * 8];
}

// ---- RMSNorm: f32 [rows][2048] -> bf16, one block per row ----
__global__ __launch_bounds__(256) void rmsnorm_k(const float* __restrict__ x,
                                                 const float* __restrict__ w,
                                                 u16* __restrict__ o) {
  const int row = blockIdx.x;
  const int t = threadIdx.x;
  const float* xr = x + (size_t)row * DIMQ;
  const float4 a = ((const float4*)xr)[t * 2];
  const float4 b = ((const float4*)xr)[t * 2 + 1];
  float ss = a.x * a.x + a.y * a.y + a.z * a.z + a.w * a.w +
             b.x * b.x + b.y * b.y + b.z * b.z + b.w * b.w;
#pragma unroll
  for (int off = 32; off > 0; off >>= 1) ss += __shfl_down(ss, off);
  __shared__ float red[4];
  if ((t & 63) == 0) red[t >> 6] = ss;
  __syncthreads();
  ss = red[0] + red[1] + red[2] + red[3];
  const float rs = rsqrtf(ss * (1.0f / (float)DIMQ) + 1e-6f);
  const float4 wa = ((const float4*)w)[t * 2];
  const float4 wb = ((const float4*)w)[t * 2 + 1];
  s16x8 ov;
  ov[0] = (short)f2bf(a.x * rs * wa.x);
  ov[1] = (short)f2bf(a.y * rs * wa.y);
  ov[2] = (short)f2bf(a.z * rs * wa.z);
  ov[3] = (short)f2bf(a.w * rs * wa.w);
  ov[4] = (short)f2bf(b.x * rs * wb.x);
  ov[5] = (short)f2bf(b.y * rs * wb.y);
  ov[6] = (short)f2bf(b.z * rs * wb.z);
  ov[7] = (short)f2bf(b.w * rs * wb.w);
  *(s16x8*)(o + (size_t)row * DIMQ + t * 8) = ov;
}

// ============================================================================
// 256xBN tile GEMM, BK=64, 8 waves, free-form 4-phase body (round-6 proven),
// with BOTH A and B prefetched at distance 2 via restage-into-current-buffer:
// all staging in ph3 after the mid-barrier; counted vmcnt(6) (BN=128) keeps
// next tile's 6 loads in flight across the tile-end barrier.
// ============================================================================
template <int OM, int BN, int ROPE>
__global__ __launch_bounds__(512, 1) void gemm256(const u16* __restrict__ A,
                                                  const u16* __restrict__ Bt,
                                                  u16* __restrict__ Cb,
                                                  float* __restrict__ Cf,
                                                  const float* __restrict__ resid,
                                                  const float* __restrict__ fc,
                                                  const float* __restrict__ fs,
                                                  int N, int K, int lda) {
  constexpr int BT = BN * 128;             // B K-tile bytes
  constexpr int BLB = BN / 128;            // gl_lds per thread per B half
  constexpr int WNv = (BN == 256) ? 4 : 2; // waves along N
  constexpr int MF = (BN == 256) ? 8 : 4;  // 16-row A frags per wave
  constexpr int MFH = MF / 2;
  __shared__ u16 lds[(65536 + 2 * BT) / 2];  // A: 0,32768; B: 65536, 65536+BT
  const int tid = threadIdx.x, wid = tid >> 6, lane = tid & 63;
  const int wm = wid / WNv, wn = wid % WNv;
  const int r = lane & 15, kc = lane >> 4;
  const int nbx = N / BN;
  const int nwg = nbx << 4;
  const int o = blockIdx.x;
  const int seq = (o & 7) * (nwg >> 3) + (o >> 3);  // XCD-chunked, row-major
  const int by = seq / nbx, bx = seq - by * nbx;
  const int m0 = by << 8, n0 = bx * BN;
  const int T = K >> 6;

  const u16* Ag = A + (size_t)m0 * lda;
  const u16* Bg = Bt + (size_t)n0 * K;

  // staging source swizzle (involution byte^=((byte>>7&7)<<4); linear LDS dest)
  const int pl = (tid * 16) ^ (((tid >> 3) & 7) << 4);
  const int prow = pl >> 7;           // = tid>>3, 0..63
  const int pcol = (pl & 127) >> 1;   // element offset within 64-elem row

  // read-side swizzled base: row r, k-chunk kc (XOR ks<<6 per k-slice)
  const int rd0 = r * 128 + ((kc * 16) ^ ((r & 7) << 4));
  const int waveA = wm * (MF * 2048);
  const int waveB = wn * 8192;

  f32x4 acc[MF][4] = {};
  s16x8 af[MFH][2], bfL[2][2], bfH[2][2];

#define STAGE_A(G, kt, BUFB, h)                                                   \
  {                                                                               \
    _Pragma("unroll") for (int i = 0; i < 2; ++i)                                 \
        gl_lds16(G + (size_t)((h) * 128 + i * 64 + prow) * lda + (kt) * 64 + pcol,\
                 (char*)lds + (BUFB) + (h) * 16384 + i * 8192 + (wid << 10));     \
  }
#define STAGE_B(G, kt, BUFB, h)                                                   \
  {                                                                               \
    _Pragma("unroll") for (int i = 0; i < BLB; ++i)                               \
        gl_lds16(G + (size_t)((h) * (BN / 2) + i * 64 + prow) * K + (kt) * 64 + pcol, \
                 (char*)lds + (BUFB) + (h) * (BT / 2) + i * 8192 + (wid << 10));  \
  }
#define VMCNT_TILE()                                                              \
  {                                                                               \
    if (BN == 128) { asm volatile("s_waitcnt vmcnt(6)" ::: "memory"); }           \
    else { asm volatile("s_waitcnt vmcnt(8)" ::: "memory"); }                     \
  }

  // prologue: tile0 -> buf0, tile1 -> buf1 (A+B each); wait tile0 landed
  STAGE_A(Ag, 0, 0, 0);
  STAGE_A(Ag, 0, 0, 1);
  STAGE_B(Bg, 0, 65536, 0);
  STAGE_B(Bg, 0, 65536, 1);
  STAGE_A(Ag, 1, 32768, 0);
  STAGE_A(Ag, 1, 32768, 1);
  STAGE_B(Bg, 1, 65536 + BT, 0);
  STAGE_B(Bg, 1, 65536 + BT, 1);
  VMCNT_TILE();
  SBAR();

#define TILE_BODY(t, cur)                                                         \
  {                                                                               \
    const int tp2 = ((t) + 2 < T) ? (t) + 2 : T - 1;                              \
    const int AB = (cur)*32768;                                                   \
    const int BB = 65536 + (cur)*BT;                                              \
    /* ---- phase 0: read A(lo)+B(lo); mfma Q(0,0) ---- */                        \
    _Pragma("unroll") for (int j = 0; j < MFH; ++j)                               \
        _Pragma("unroll") for (int ks = 0; ks < 2; ++ks)                          \
            af[j][ks] = *(const s16x8*)((const char*)lds + AB + waveA +           \
                                        j * 2048 + (rd0 ^ (ks << 6)));            \
    _Pragma("unroll") for (int n = 0; n < 2; ++n)                                 \
        _Pragma("unroll") for (int ks = 0; ks < 2; ++ks)                          \
            bfL[n][ks] = *(const s16x8*)((const char*)lds + BB + waveB +          \
                                         n * 2048 + (rd0 ^ (ks << 6)));           \
    __builtin_amdgcn_s_setprio(1);                                                \
    _Pragma("unroll") for (int ks = 0; ks < 2; ++ks)                              \
        _Pragma("unroll") for (int j = 0; j < MFH; ++j)                           \
            _Pragma("unroll") for (int n = 0; n < 2; ++n)                         \
                acc[j][n] = mfma16(af[j][ks], bfL[n][ks], acc[j][n]);             \
    __builtin_amdgcn_s_setprio(0);                                                \
    /* ---- phase 1: read B(hi); mfma Q(0,1) ---- */                              \
    _Pragma("unroll") for (int n = 0; n < 2; ++n)                                 \
        _Pragma("unroll") for (int ks = 0; ks < 2; ++ks)                          \
            bfH[n][ks] = *(const s16x8*)((const char*)lds + BB + waveB +          \
                                         (2 + n) * 2048 + (rd0 ^ (ks << 6)));     \
    __builtin_amdgcn_s_setprio(1);                                                \
    _Pragma("unroll") for (int ks = 0; ks < 2; ++ks)                              \
        _Pragma("unroll") for (int j = 0; j < MFH; ++j)                           \
            _Pragma("unroll") for (int n = 0; n < 2; ++n)                         \
                acc[j][2 + n] = mfma16(af[j][ks], bfH[n][ks], acc[j][2 + n]);     \
    __builtin_amdgcn_s_setprio(0);                                                \
    /* ---- phase 2: read A(hi); mfma Q(1,0) ---- */                              \
    _Pragma("unroll") for (int j = 0; j < MFH; ++j)                               \
        _Pragma("unroll") for (int ks = 0; ks < 2; ++ks)                          \
            af[j][ks] = *(const s16x8*)((const char*)lds + AB + waveA +           \
                                        (MFH + j) * 2048 + (rd0 ^ (ks << 6)));    \
    __builtin_amdgcn_s_setprio(1);                                                \
    _Pragma("unroll") for (int ks = 0; ks < 2; ++ks)                              \
        _Pragma("unroll") for (int j = 0; j < MFH; ++j)                           \
            _Pragma("unroll") for (int n = 0; n < 2; ++n)                         \
                acc[MFH + j][n] = mfma16(af[j][ks], bfL[n][ks], acc[MFH + j][n]); \
    __builtin_amdgcn_s_setprio(0);                                                \
    LGKM0(); /* all LDS reads of this tile complete */                            \
    SBAR();  /* -> safe to overwrite BOTH current buffers */                      \
    /* ---- phase 3: stage A(t+2)->AB and B(t+2)->BB; mfma Q(1,1) ---- */         \
    STAGE_A(Ag, tp2, AB, 0);                                                      \
    STAGE_A(Ag, tp2, AB, 1);                                                      \
    STAGE_B(Bg, tp2, BB, 0);                                                      \
    STAGE_B(Bg, tp2, BB, 1);                                                      \
    __builtin_amdgcn_s_setprio(1);                                                \
    _Pragma("unroll") for (int ks = 0; ks < 2; ++ks)                              \
        _Pragma("unroll") for (int j = 0; j < MFH; ++j)                           \
            _Pragma("unroll") for (int n = 0; n < 2; ++n)                         \
                acc[MFH + j][2 + n] = mfma16(af[j][ks], bfH[n][ks], acc[MFH + j][2 + n]); \
    __builtin_amdgcn_s_setprio(0);                                                \
    VMCNT_TILE(); /* tile t+1 (A+B) landed; t+2 stays in flight */                \
    SBAR();                                                                       \
  }

  for (int tt = 0; tt < T; tt += 2) {  // T even for all shapes (32, 88)
    TILE_BODY(tt, 0);
    TILE_BODY(tt + 1, 1);
  }
#undef TILE_BODY
#undef STAGE_A
#undef STAGE_B
#undef VMCNT_TILE

  const bool do_rope = ROPE && (n0 < 4096);
#pragma unroll
  for (int mf = 0; mf < MF; ++mf)
#pragma unroll
    for (int nf = 0; nf < 4; ++nf)
#pragma unroll
      for (int j = 0; j < 4; ++j) {
        const int rr = m0 + wm * (MF * 16) + mf * 16 + kc * 4 + j;
        const int cc = n0 + wn * 64 + nf * 16 + r;
        float v = acc[mf][nf][j];
        if (OM == 0) {
          if (ROPE) {  // fused RoPE: lanes r, r^1 hold (re,im) of one pair
            const float partner = __shfl_xor(v, 1);
            if (do_rope) {
              const int s = rr & (SQ - 1);
              const int i0 = (cc >> 1) & 63;
              const float cv = fc[s * 64 + i0];
              const float sv = fs[s * 64 + i0];
              v = ((r & 1) == 0) ? v * cv - partner * sv : v * cv + partner * sv;
            }
          }
          Cb[(size_t)rr * N + cc] = f2bf(v);
        } else {
          Cf[(size_t)rr * N + cc] = v + resid[(size_t)rr * N + cc];
        }
      }
}

// ============================================================================
// Fused FFN GEMM: act[4096][5632] = silu(f_in@w1) * (f_in@w3), bf16 out.
// Free-form body; A+B both distance-2 prefetched in ph3; vmcnt(8).
// ============================================================================
__global__ __launch_bounds__(512, 1) void gemm_ffn(const u16* __restrict__ A,
                                                   const u16* __restrict__ Bi,
                                                   u16* __restrict__ act) {
  __shared__ u16 lds[65536];  // A bufs @0,32768; B bufs @65536,98304 (bytes)
  const int tid = threadIdx.x, wid = tid >> 6, lane = tid & 63;
  const int wm = wid >> 1, wn = wid & 1;
  const int r = lane & 15, kc = lane >> 4;
  const int o = blockIdx.x;                 // 704 blocks = 16 m x 44 chunks
  const int seq = (o & 7) * 88 + (o >> 3);  // XCD-chunked, row-major
  const int by = seq / 44, bx = seq - by * 44;
  const int m0 = by << 8;
  const int T = 32;  // K = 2048

  const u16* Ag = A + (size_t)m0 * DIMQ;
  const u16* Bg = Bi + (size_t)bx * 256 * DIMQ;

  const int pl = (tid * 16) ^ (((tid >> 3) & 7) << 4);
  const int prow = pl >> 7, pcol = (pl & 127) >> 1;
  const int rd0 = r * 128 + ((kc * 16) ^ ((r & 7) << 4));
  const int waveA = wm * 8192;  // 64 rows
  const int waveB = wn * 8192;  // 64 gate rows (up at +16384)

  f32x4 accG[4][4] = {}, accU[4][4] = {};
  s16x8 af[4][2], bL[2][2], bH[2][2];

#define STG(G, kt, BUFB, h)                                                       \
  {                                                                               \
    _Pragma("unroll") for (int i = 0; i < 2; ++i)                                 \
        gl_lds16(G + (size_t)((h) * 128 + i * 64 + prow) * DIMQ + (kt) * 64 + pcol,\
                 (char*)lds + (BUFB) + (h) * 16384 + i * 8192 + (wid << 10));     \
  }

  // prologue: tile0 -> buf0, tile1 -> buf1 (A+B); wait tile0's 8 loads
  STG(Ag, 0, 0, 0);
  STG(Ag, 0, 0, 1);
  STG(Bg, 0, 65536, 0);
  STG(Bg, 0, 65536, 1);
  STG(Ag, 1, 32768, 0);
  STG(Ag, 1, 32768, 1);
  STG(Bg, 1, 98304, 0);
  STG(Bg, 1, 98304, 1);
  asm volatile("s_waitcnt vmcnt(8)" ::: "memory");
  SBAR();

#define FFN_BODY(t, cur)                                                          \
  {                                                                               \
    const int tp2 = ((t) + 2 < T) ? (t) + 2 : T - 1;                              \
    const int AB = (cur)*32768;                                                   \
    const int BB = 65536 + (cur)*32768;                                           \
    /* ph0: read af + gate-lo; mfma G01 */                                        \
    _Pragma("unroll") for (int j = 0; j < 4; ++j)                                 \
        _Pragma("unroll") for (int ks = 0; ks < 2; ++ks)                          \
            af[j][ks] = *(const s16x8*)((const char*)lds + AB + waveA +           \
                                        j * 2048 + (rd0 ^ (ks << 6)));            \
    _Pragma("unroll") for (int n = 0; n < 2; ++n)                                 \
        _Pragma("unroll") for (int ks = 0; ks < 2; ++ks)                          \
            bL[n][ks] = *(const s16x8*)((const char*)lds + BB + waveB +           \
                                        n * 2048 + (rd0 ^ (ks << 6)));            \
    __builtin_amdgcn_s_setprio(1);                                                \
    _Pragma("unroll") for (int ks = 0; ks < 2; ++ks)                              \
        _Pragma("unroll") for (int j = 0; j < 4; ++j)                             \
            _Pragma("unroll") for (int n = 0; n < 2; ++n)                         \
                accG[j][n] = mfma16(af[j][ks], bL[n][ks], accG[j][n]);            \
    __builtin_amdgcn_s_setprio(0);                                                \
    /* ph1: read gate-hi; mfma G23 */                                             \
    _Pragma("unroll") for (int n = 0; n < 2; ++n)                                 \
        _Pragma("unroll") for (int ks = 0; ks < 2; ++ks)                          \
            bH[n][ks] = *(const s16x8*)((const char*)lds + BB + waveB +           \
                                        (2 + n) * 2048 + (rd0 ^ (ks << 6)));      \
    __builtin_amdgcn_s_setprio(1);                                                \
    _Pragma("unroll") for (int ks = 0; ks < 2; ++ks)                              \
        _Pragma("unroll") for (int j = 0; j < 4; ++j)                             \
            _Pragma("unroll") for (int n = 0; n < 2; ++n)                         \
                accG[j][2 + n] = mfma16(af[j][ks], bH[n][ks], accG[j][2 + n]);    \
    __builtin_amdgcn_s_setprio(0);                                                \
    /* ph2: read up-lo; mfma U01; read up-hi */                                   \
    _Pragma("unroll") for (int n = 0; n < 2; ++n)                                 \
        _Pragma("unroll") for (int ks = 0; ks < 2; ++ks)                          \
            bL[n][ks] = *(const s16x8*)((const char*)lds + BB + 16384 + waveB +   \
                                        n * 2048 + (rd0 ^ (ks << 6)));            \
    __builtin_amdgcn_s_setprio(1);                                                \
    _Pragma("unroll") for (int ks = 0; ks < 2; ++ks)                              \
        _Pragma("unroll") for (int j = 0; j < 4; ++j)                             \
            _Pragma("unroll") for (int n = 0; n < 2; ++n)                         \
                accU[j][n] = mfma16(af[j][ks], bL[n][ks], accU[j][n]);            \
    __builtin_amdgcn_s_setprio(0);                                                \
    _Pragma("unroll") for (int n = 0; n < 2; ++n)                                 \
        _Pragma("unroll") for (int ks = 0; ks < 2; ++ks)                          \
            bH[n][ks] = *(const s16x8*)((const char*)lds + BB + 16384 + waveB +   \
                                        (2 + n) * 2048 + (rd0 ^ (ks << 6)));      \
    LGKM0(); /* up-hi reads complete before buffer overwrite */                   \
    SBAR();                                                                       \
    /* ph3: stage A(t+2)->AB, B(t+2)->BB; mfma U23 */                             \
    STG(Ag, tp2, AB, 0);                                                          \
    STG(Ag, tp2, AB, 1);                                                          \
    STG(Bg, tp2, BB, 0);                                                          \
    STG(Bg, tp2, BB, 1);                                                          \
    __builtin_amdgcn_s_setprio(1);                                                \
    _Pragma("unroll") for (int ks = 0; ks < 2; ++ks)                              \
        _Pragma("unroll") for (int j = 0; j < 4; ++j)                             \
            _Pragma("unroll") for (int n = 0; n < 2; ++n)                         \
                accU[j][2 + n] = mfma16(af[j][ks], bH[n][ks], accU[j][2 + n]);    \
    __builtin_amdgcn_s_setprio(0);                                                \
    asm volatile("s_waitcnt vmcnt(8)" ::: "memory");                              \
    SBAR();                                                                       \
  }

  for (int tt = 0; tt < T; tt += 2) {
    FFN_BODY(tt, 0);
    FFN_BODY(tt + 1, 1);
  }
#undef FFN_BODY
#undef STG

  const int cbase = bx * 128 + wn * 64;
#pragma unroll
  for (int mf = 0; mf < 4; ++mf)
#pragma unroll
    for (int nf = 0; nf < 4; ++nf)
#pragma unroll
      for (int j = 0; j < 4; ++j) {
        const int rr = m0 + wm * 64 + mf * 16 + kc * 4 + j;
        const int cc = cbase + nf * 16 + r;
        const float g = accG[mf][nf][j];
        const float u = accU[mf][nf][j];
        const float a = g / (1.f + __expf(-g)) * u;
        act[(size_t)rr * HIDQ + cc] = f2bf(a);
      }
}

// ============================================================================
// Causal flash attention, diagonal-paired for uniform makespan.
// ============================================================================
__global__ __launch_bounds__(512) void attn_k(const u16* __restrict__ qkv,
                                              const u16* __restrict__ vt,
                                              u16* __restrict__ outb) {
  __shared__ u16 Kl[64 * 136];      // [key][d], stride 136
  __shared__ u16 Vl[128 * 72];      // [d][key], stride 72
  __shared__ u16 Pl[8][16 * 80];    // per-wave P tile [qrow][key]
  const int bh = blockIdx.x;
  const int pr = blockIdx.y;         // 0..15
  const int b = bh >> 4, h = bh & 15;
  const int tid = threadIdx.x, wid = tid >> 6, lane = tid & 63;
  const int r = lane & 15, kc = lane >> 4;
  const int nt_lo = pr + 1, nt = 32 - pr;
  const int qbase = ((wid < 4) ? pr * 64 : (31 - pr) * 64) + (wid & 3) * 16;
  const size_t base = (size_t)b * SQ * 6144;
  const u16* vtb = vt + (size_t)bh * HDQ * SQ;
  s16x8 qf[4];
  {
    const size_t qoff = base + (size_t)(qbase + r) * 6144 + h * HDQ;
#pragma unroll
    for (int kk = 0; kk < 4; ++kk)
      qf[kk] = *(const s16x8*)&qkv[qoff + kk * 32 + kc * 8];
  }
  f32x4 acc_o[8] = {};
  float m_run[4], l_run[4];
#pragma unroll
  for (int j = 0; j < 4; ++j) { m_run[j] = -1e30f; l_run[j] = 0.f; }
  // staging indices (512 threads)
  const int kr = tid >> 4, kc8 = (tid & 15) * 8;   // K: rows kr, kr+32; 128 elems
  const int vr = tid >> 3, vc8 = (tid & 7) * 8;    // V: rows vr, vr+64; 64 elems
  const u16* kgp = &qkv[base + (size_t)kr * 6144 + 2048 + h * HDQ + kc8];
  const u16* vgp = &vtb[(size_t)vr * SQ + vc8];
  s16x8 kreg[2], vreg[2];
  kreg[0] = *(const s16x8*)kgp;
  kreg[1] = *(const s16x8*)(kgp + (size_t)32 * 6144);
  vreg[0] = *(const s16x8*)vgp;
  vreg[1] = *(const s16x8*)(vgp + (size_t)64 * SQ);
  for (int t = 0; t < nt; ++t) {
    const int kv0 = t * 64;
    __syncthreads();  // previous tile's LDS reads done
    *(s16x8*)&Kl[kr * 136 + kc8] = kreg[0];
    *(s16x8*)&Kl[(kr + 32) * 136 + kc8] = kreg[1];
    *(s16x8*)&Vl[vr * 72 + vc8] = vreg[0];
    *(s16x8*)&Vl[(vr + 64) * 72 + vc8] = vreg[1];
    __syncthreads();
    if (t + 1 < nt) {  // issue next tile's loads; land under compute (T14)
      const u16* kg = kgp + (size_t)(kv0 + 64) * 6144;
      const u16* vg = vgp + (kv0 + 64);
      kreg[0] = *(const s16x8*)kg;
      kreg[1] = *(const s16x8*)(kg + (size_t)32 * 6144);
      vreg[0] = *(const s16x8*)vg;
      vreg[1] = *(const s16x8*)(vg + (size_t)64 * SQ);
    }
    if (wid >= 4 || t < nt_lo) {
      // S = Q*K^T for this wave's 16 q-rows x 64 keys
      f32x4 sacc[4] = {};
      __builtin_amdgcn_s_setprio(1);
#pragma unroll
      for (int nf = 0; nf < 4; ++nf)
#pragma unroll
        for (int kk = 0; kk < 4; ++kk) {
          const s16x8 kf = *(const s16x8*)&Kl[(nf * 16 + r) * 136 + kk * 32 + kc * 8];
          sacc[nf] = mfma16(qf[kk], kf, sacc[nf]);
        }
      __builtin_amdgcn_s_setprio(0);
      // online softmax
      float p[4][4], alpha[4];
#pragma unroll
      for (int j = 0; j < 4; ++j) {
        const int qrow = qbase + kc * 4 + j;
        float svs[4];
        float tm = -1e30f;
#pragma unroll
        for (int nf = 0; nf < 4; ++nf) {
          const int key = kv0 + nf * 16 + r;
          float sv = sacc[nf][j] * SC_ATTN;
          sv = (key > qrow) ? -1e30f : sv;
          svs[nf] = sv;
          tm = fmaxf(tm, sv);
        }
        tm = fmaxf(tm, __shfl_xor(tm, 1));
        tm = fmaxf(tm, __shfl_xor(tm, 2));
        tm = fmaxf(tm, __shfl_xor(tm, 4));
        tm = fmaxf(tm, __shfl_xor(tm, 8));
        const float mnew = fmaxf(m_run[j], tm);
        alpha[j] = __expf(m_run[j] - mnew);
        m_run[j] = mnew;
        float rs = 0.f;
#pragma unroll
        for (int nf = 0; nf < 4; ++nf) {
          const float pv = __expf(svs[nf] - mnew);
          p[nf][j] = pv;
          rs += pv;
        }
        rs += __shfl_xor(rs, 1);
        rs += __shfl_xor(rs, 2);
        rs += __shfl_xor(rs, 4);
        rs += __shfl_xor(rs, 8);
        l_run[j] = l_run[j] * alpha[j] + rs;
      }
#pragma unroll
      for (int nf = 0; nf < 8; ++nf)
#pragma unroll
        for (int j = 0; j < 4; ++j)
          acc_o[nf][j] *= alpha[j];
      // P (D-layout) -> per-wave LDS -> A-layout fragments
#pragma unroll
      for (int nf = 0; nf < 4; ++nf)
#pragma unroll
        for (int j = 0; j < 4; ++j)
          Pl[wid][(kc * 4 + j) * 80 + nf * 16 + r] = f2bf(p[nf][j]);
      __builtin_amdgcn_s_setprio(1);
#pragma unroll
      for (int ks = 0; ks < 2; ++ks) {
        const s16x8 pa = *(const s16x8*)&Pl[wid][r * 80 + ks * 32 + kc * 8];
#pragma unroll
        for (int nf = 0; nf < 8; ++nf) {
          const s16x8 bv = *(const s16x8*)&Vl[(nf * 16 + r) * 72 + ks * 32 + kc * 8];
          acc_o[nf] = mfma16(pa, bv, acc_o[nf]);
        }
      }
      __builtin_amdgcn_s_setprio(0);
    }
  }
#pragma unroll
  for (int j = 0; j < 4; ++j) {
    const float inv = 1.0f / l_run[j];
    const size_t orow = (size_t)(b * SQ + qbase + kc * 4 + j) * DIMQ + h * HDQ;
#pragma unroll
    for (int nf = 0; nf < 8; ++nf)
      outb[orow + nf * 16 + r] = f2bf(acc_o[nf][j] * inv);
  }
}

extern "C" void kernel_launch(void* const* d_in, const int* in_sizes, int n_in,
                              void* d_out, int out_size, void* d_ws, size_t ws_size,
                              hipStream_t stream) {
  const float* x   = (const float*)d_in[0];
  const float* wq  = (const float*)d_in[1];
  const float* wk  = (const float*)d_in[2];
  const float* wv  = (const float*)d_in[3];
  const float* wo  = (const float*)d_in[4];
  const float* w1  = (const float*)d_in[5];
  const float* w2  = (const float*)d_in[6];  // note: w2 comes before w3 in dict order
  const float* w3  = (const float*)d_in[7];
  const float* anw = (const float*)d_in[8];
  const float* fnw = (const float*)d_in[9];
  const float* fc  = (const float*)d_in[10];
  const float* fs  = (const float*)d_in[11];
  float* out = (float*)d_out;

  char* ws = (char*)d_ws;
  // weights (bf16, transposed)
  u16* wqkvT = (u16*)(ws);                                  // [6144][2048]
  u16* woT   = (u16*)(ws + 25165824);                       // [2048][2048]
  u16* w13i  = (u16*)(ws + 25165824 + 8388608);             // [11264][2048] interleaved
  u16* w2T   = (u16*)(ws + 25165824 + 8388608 + 46137344);  // [2048][5632]
  // activations
  u16* hin   = (u16*)(ws + 102760448);                      // [4096][2048] bf16
  u16* qkvb  = (u16*)(ws + 119537664);                      // attn: [4096][6144]; FFN: act [4096][5632]
  u16* act   = qkvb;
  u16* attnb = (u16*)(ws + 119537664 + 50331648);           // [4096][2048] bf16
  u16* vtb   = (u16*)(ws + 119537664 + 50331648 + 16777216);// [32][128][2048] bf16
  float* h = out;                                           // h lives in d_out

  const dim3 tb(32, 8);
  transpose_cvt<<<dim3(64, 64), tb, 0, stream>>>(wq, wqkvT, 2048, 2048);
  transpose_cvt<<<dim3(64, 64), tb, 0, stream>>>(wk, wqkvT + (size_t)2048 * 2048, 2048, 2048);
  transpose_cvt<<<dim3(64, 64), tb, 0, stream>>>(wv, wqkvT + (size_t)2 * 2048 * 2048, 2048, 2048);
  transpose_cvt<<<dim3(64, 64), tb, 0, stream>>>(wo, woT, 2048, 2048);
  transpose_cvt_ffn<<<dim3(176, 64), tb, 0, stream>>>(w1, w13i, 0);
  transpose_cvt_ffn<<<dim3(176, 64), tb, 0, stream>>>(w3, w13i, 128);
  transpose_cvt<<<dim3(64, 176), tb, 0, stream>>>(w2, w2T, 5632, 2048);

  rmsnorm_k<<<4096, 256, 0, stream>>>(x, anw, hin);
  gemm256<0, 128, 1><<<768, 512, 0, stream>>>(hin, wqkvT, qkvb, nullptr, nullptr, fc, fs, 6144, 2048, 2048);
  vtrans_k<<<dim3(64, 4, 32), tb, 0, stream>>>(qkvb, vtb);
  attn_k<<<dim3(32, 16), 512, 0, stream>>>(qkvb, vtb, attnb);
  gemm256<1, 128, 0><<<256, 512, 0, stream>>>(attnb, woT, nullptr, h, x, nullptr, nullptr, 2048, 2048, 2048);
  rmsnorm_k<<<4096, 256, 0, stream>>>(h, fnw, hin);
  gemm_ffn<<<704, 512, 0, stream>>>(hin, w13i, act);
  gemm256<1, 128, 0><<<256, 512, 0, stream>>>(act, w2T, nullptr, out, h, nullptr, nullptr, 2048, 5632, 5632);
}

// Round 12
// 639.612 us; speedup vs baseline: 1.0155x; 1.0155x over previous
//
#include <hip/hip_runtime.h>

// ---- problem constants ----
#define DIMQ 2048
#define NHQ  16
#define HDQ  128
#define BQ   2
#define SQ   2048
#define HIDQ 5632
#define MQ   (BQ * SQ)   // 4096
#define SC_ATTN 0.08838834764831845f  // 1/sqrt(128)

using u16 = unsigned short;
using u32 = unsigned int;
typedef __attribute__((ext_vector_type(8))) short s16x8;
typedef __attribute__((ext_vector_type(4))) float f32x4;

__device__ __forceinline__ float bf2f(u16 v) {
  union { u32 u; float f; } w; w.u = ((u32)v) << 16; return w.f;
}
__device__ __forceinline__ u16 f2bf(float f) {
  union { float f; u32 u; } w; w.f = f;
  u32 r = w.u + 0x7FFFu + ((w.u >> 16) & 1u);  // RNE
  return (u16)(r >> 16);
}

__device__ __forceinline__ f32x4 mfma16(s16x8 a, s16x8 b, f32x4 c) {
  return __builtin_amdgcn_mfma_f32_16x16x32_bf16(a, b, c, 0, 0, 0);
}

// async global->LDS, 16B per lane; LDS dest is wave-uniform base + lane*16
__device__ __forceinline__ void gl_lds16(const void* g, void* l) {
  __builtin_amdgcn_global_load_lds((const __attribute__((address_space(1))) void*)g,
                                   (__attribute__((address_space(3))) void*)l,
                                   16, 0, 0);
}

#define SBAR()                                   \
  {                                              \
    asm volatile("" ::: "memory");               \
    __builtin_amdgcn_s_barrier();                \
    asm volatile("" ::: "memory");               \
  }
#define LGKM0() asm volatile("s_waitcnt lgkmcnt(0)" ::: "memory")

// ---- weight transpose + fp32->bf16 convert: src[R][Cn] f32 -> dst[Cn][R] bf16 ----
__global__ __launch_bounds__(256) void transpose_cvt(const float* __restrict__ src,
                                                     u16* __restrict__ dst,
                                                     int R, int Cn) {
  __shared__ float tile[32][33];
  const int tx = threadIdx.x, ty = threadIdx.y;
  const int c0 = blockIdx.x * 32, r0 = blockIdx.y * 32;
#pragma unroll
  for (int i = 0; i < 4; ++i)
    tile[ty + i * 8][tx] = src[(size_t)(r0 + ty + i * 8) * Cn + c0 + tx];
  __syncthreads();
#pragma unroll
  for (int i = 0; i < 4; ++i)
    dst[(size_t)(c0 + ty + i * 8) * R + r0 + tx] = f2bf(tile[tx][ty + i * 8]);
}

// ---- FFN weight transpose with gate/up interleave: src[2048][5632] f32 ->
// dst row' = (n>>7)*256 + base + (n&127). ----
__global__ __launch_bounds__(256) void transpose_cvt_ffn(const float* __restrict__ src,
                                                         u16* __restrict__ dst,
                                                         int base) {
  __shared__ float tile[32][33];
  const int tx = threadIdx.x, ty = threadIdx.y;
  const int c0 = blockIdx.x * 32, r0 = blockIdx.y * 32;  // c0 over 5632, r0 over 2048
#pragma unroll
  for (int i = 0; i < 4; ++i)
    tile[ty + i * 8][tx] = src[(size_t)(r0 + ty + i * 8) * HIDQ + c0 + tx];
  __syncthreads();
#pragma unroll
  for (int i = 0; i < 4; ++i) {
    const int n = c0 + ty + i * 8;
    const int row = (n >> 7) * 256 + base + (n & 127);
    dst[(size_t)row * DIMQ + r0 + tx] = f2bf(tile[tx][ty + i * 8]);
  }
}

// ---- V transpose: qkv v-slice [s][d] bf16 -> Vt[bh][d][s] bf16 ----
__global__ __launch_bounds__(256) void vtrans_k(const u16* __restrict__ qkv,
                                                u16* __restrict__ vt) {
  __shared__ u16 tile[32][33];
  const int bh = blockIdx.z;
  const int b = bh >> 4, h = bh & 15;
  const int s0 = blockIdx.x * 32, d0 = blockIdx.y * 32;
  const int tx = threadIdx.x, ty = threadIdx.y;
  const u16* src = qkv + (size_t)(b * SQ) * 6144 + 4096 + h * HDQ;
#pragma unroll
  for (int i = 0; i < 4; ++i)
    tile[ty + i * 8][tx] = src[(size_t)(s0 + ty + i * 8) * 6144 + d0 + tx];
  __syncthreads();
  u16* dst = vt + (size_t)bh * HDQ * SQ;
#pragma unroll
  for (int i = 0; i < 4; ++i)
    dst[(size_t)(d0 + ty + i * 8) * SQ + s0 + tx] = tile[tx][ty + i * 8];
}

// ---- RMSNorm: f32 [rows][2048] -> bf16, one block per row ----
__global__ __launch_bounds__(256) void rmsnorm_k(const float* __restrict__ x,
                                                 const float* __restrict__ w,
                                                 u16* __restrict__ o) {
  const int row = blockIdx.x;
  const int t = threadIdx.x;
  const float* xr = x + (size_t)row * DIMQ;
  const float4 a = ((const float4*)xr)[t * 2];
  const float4 b = ((const float4*)xr)[t * 2 + 1];
  float ss = a.x * a.x + a.y * a.y + a.z * a.z + a.w * a.w +
             b.x * b.x + b.y * b.y + b.z * b.z + b.w * b.w;
#pragma unroll
  for (int off = 32; off > 0; off >>= 1) ss += __shfl_down(ss, off);
  __shared__ float red[4];
  if ((t & 63) == 0) red[t >> 6] = ss;
  __syncthreads();
  ss = red[0] + red[1] + red[2] + red[3];
  const float rs = rsqrtf(ss * (1.0f / (float)DIMQ) + 1e-6f);
  const float4 wa = ((const float4*)w)[t * 2];
  const float4 wb = ((const float4*)w)[t * 2 + 1];
  s16x8 ov;
  ov[0] = (short)f2bf(a.x * rs * wa.x);
  ov[1] = (short)f2bf(a.y * rs * wa.y);
  ov[2] = (short)f2bf(a.z * rs * wa.z);
  ov[3] = (short)f2bf(a.w * rs * wa.w);
  ov[4] = (short)f2bf(b.x * rs * wb.x);
  ov[5] = (short)f2bf(b.y * rs * wb.y);
  ov[6] = (short)f2bf(b.z * rs * wb.z);
  ov[7] = (short)f2bf(b.w * rs * wb.w);
  *(s16x8*)(o + (size_t)row * DIMQ + t * 8) = ov;
}

// ============================================================================
// 256xBN tile GEMM, BK=64, 8 waves, round-6 free-form 4-phase body (633us
// baseline): B(t+1) staged ph0/ph1, A(t+2) staged ph3, counted vmcnt(4).
// ============================================================================
template <int OM, int BN, int ROPE>
__global__ __launch_bounds__(512, 1) void gemm256(const u16* __restrict__ A,
                                                  const u16* __restrict__ Bt,
                                                  u16* __restrict__ Cb,
                                                  float* __restrict__ Cf,
                                                  const float* __restrict__ resid,
                                                  const float* __restrict__ fc,
                                                  const float* __restrict__ fs,
                                                  int N, int K, int lda) {
  constexpr int BT = BN * 128;             // B K-tile bytes
  constexpr int BLB = BN / 128;            // gl_lds per thread per B half
  constexpr int WNv = (BN == 256) ? 4 : 2; // waves along N
  constexpr int MF = (BN == 256) ? 8 : 4;  // 16-row A frags per wave
  constexpr int MFH = MF / 2;
  __shared__ u16 lds[(65536 + 2 * BT) / 2];  // A: 0,32768; B: 65536, 65536+BT
  const int tid = threadIdx.x, wid = tid >> 6, lane = tid & 63;
  const int wm = wid / WNv, wn = wid % WNv;
  const int r = lane & 15, kc = lane >> 4;
  const int nbx = N / BN;
  const int nwg = nbx << 4;
  const int o = blockIdx.x;
  const int seq = (o & 7) * (nwg >> 3) + (o >> 3);  // XCD-chunked, row-major
  const int by = seq / nbx, bx = seq - by * nbx;
  const int m0 = by << 8, n0 = bx * BN;
  const int T = K >> 6;

  const u16* Ag = A + (size_t)m0 * lda;
  const u16* Bg = Bt + (size_t)n0 * K;

  // staging source swizzle (involution byte^=((byte>>7&7)<<4); linear LDS dest)
  const int pl = (tid * 16) ^ (((tid >> 3) & 7) << 4);
  const int prow = pl >> 7;           // = tid>>3, 0..63
  const int pcol = (pl & 127) >> 1;   // element offset within 64-elem row

  // read-side swizzled base: row r, k-chunk kc (XOR ks<<6 per k-slice)
  const int rd0 = r * 128 + ((kc * 16) ^ ((r & 7) << 4));
  const int waveA = wm * (MF * 2048);
  const int waveB = wn * 8192;

  f32x4 acc[MF][4] = {};
  s16x8 af[MFH][2], bfL[2][2], bfH[2][2];

#define STAGE_A(G, kt, BUFB, h)                                                   \
  {                                                                               \
    _Pragma("unroll") for (int i = 0; i < 2; ++i)                                 \
        gl_lds16(G + (size_t)((h) * 128 + i * 64 + prow) * lda + (kt) * 64 + pcol,\
                 (char*)lds + (BUFB) + (h) * 16384 + i * 8192 + (wid << 10));     \
  }
#define STAGE_B(G, kt, BUFB, h)                                                   \
  {                                                                               \
    _Pragma("unroll") for (int i = 0; i < BLB; ++i)                               \
        gl_lds16(G + (size_t)((h) * (BN / 2) + i * 64 + prow) * K + (kt) * 64 + pcol, \
                 (char*)lds + (BUFB) + (h) * (BT / 2) + i * 8192 + (wid << 10));  \
  }

  // prologue: tile0 A+B -> buf0; tile1 A -> buf1
  STAGE_A(Ag, 0, 0, 0);
  STAGE_A(Ag, 0, 0, 1);
  STAGE_B(Bg, 0, 65536, 0);
  STAGE_B(Bg, 0, 65536, 1);
  STAGE_A(Ag, 1, 32768, 0);
  STAGE_A(Ag, 1, 32768, 1);
  asm volatile("s_waitcnt vmcnt(4)" ::: "memory");
  SBAR();

#define TILE_BODY(t, cur)                                                         \
  {                                                                               \
    const int tp1 = ((t) + 1 < T) ? (t) + 1 : T - 1;                              \
    const int tp2 = ((t) + 2 < T) ? (t) + 2 : T - 1;                              \
    const int AB = (cur)*32768;                                                   \
    const int BB = 65536 + (cur)*BT;                                              \
    const int BBn = 65536 + (1 - (cur)) * BT;                                     \
    /* ---- phase 0: stage B.h0(t+1); read A(lo)+B(lo); mfma Q(0,0) ---- */       \
    STAGE_B(Bg, tp1, BBn, 0);                                                     \
    _Pragma("unroll") for (int j = 0; j < MFH; ++j)                               \
        _Pragma("unroll") for (int ks = 0; ks < 2; ++ks)                          \
            af[j][ks] = *(const s16x8*)((const char*)lds + AB + waveA +           \
                                        j * 2048 + (rd0 ^ (ks << 6)));            \
    _Pragma("unroll") for (int n = 0; n < 2; ++n)                                 \
        _Pragma("unroll") for (int ks = 0; ks < 2; ++ks)                          \
            bfL[n][ks] = *(const s16x8*)((const char*)lds + BB + waveB +          \
                                         n * 2048 + (rd0 ^ (ks << 6)));           \
    __builtin_amdgcn_s_setprio(1);                                                \
    _Pragma("unroll") for (int ks = 0; ks < 2; ++ks)                              \
        _Pragma("unroll") for (int j = 0; j < MFH; ++j)                           \
            _Pragma("unroll") for (int n = 0; n < 2; ++n)                         \
                acc[j][n] = mfma16(af[j][ks], bfL[n][ks], acc[j][n]);             \
    __builtin_amdgcn_s_setprio(0);                                                \
    /* ---- phase 1: stage B.h1(t+1); read B(hi); mfma Q(0,1) ---- */             \
    STAGE_B(Bg, tp1, BBn, 1);                                                     \
    _Pragma("unroll") for (int n = 0; n < 2; ++n)                                 \
        _Pragma("unroll") for (int ks = 0; ks < 2; ++ks)                          \
            bfH[n][ks] = *(const s16x8*)((const char*)lds + BB + waveB +          \
                                         (2 + n) * 2048 + (rd0 ^ (ks << 6)));     \
    __builtin_amdgcn_s_setprio(1);                                                \
    _Pragma("unroll") for (int ks = 0; ks < 2; ++ks)                              \
        _Pragma("unroll") for (int j = 0; j < MFH; ++j)                           \
            _Pragma("unroll") for (int n = 0; n < 2; ++n)                         \
                acc[j][2 + n] = mfma16(af[j][ks], bfH[n][ks], acc[j][2 + n]);     \
    __builtin_amdgcn_s_setprio(0);                                                \
    /* ---- phase 2: read A(hi); mfma Q(1,0) ---- */                              \
    _Pragma("unroll") for (int j = 0; j < MFH; ++j)                               \
        _Pragma("unroll") for (int ks = 0; ks < 2; ++ks)                          \
            af[j][ks] = *(const s16x8*)((const char*)lds + AB + waveA +           \
                                        (MFH + j) * 2048 + (rd0 ^ (ks << 6)));    \
    __builtin_amdgcn_s_setprio(1);                                                \
    _Pragma("unroll") for (int ks = 0; ks < 2; ++ks)                              \
        _Pragma("unroll") for (int j = 0; j < MFH; ++j)                           \
            _Pragma("unroll") for (int n = 0; n < 2; ++n)                         \
                acc[MFH + j][n] = mfma16(af[j][ks], bfL[n][ks], acc[MFH + j][n]); \
    __builtin_amdgcn_s_setprio(0);                                                \
    SBAR(); /* all reads of buf[cur] done -> safe to overwrite its A region */    \
    /* ---- phase 3: stage A(t+2) into buf[cur]; mfma Q(1,1) ---- */              \
    STAGE_A(Ag, tp2, AB, 0);                                                      \
    STAGE_A(Ag, tp2, AB, 1);                                                      \
    __builtin_amdgcn_s_setprio(1);                                                \
    _Pragma("unroll") for (int ks = 0; ks < 2; ++ks)                              \
        _Pragma("unroll") for (int j = 0; j < MFH; ++j)                           \
            _Pragma("unroll") for (int n = 0; n < 2; ++n)                         \
                acc[MFH + j][2 + n] = mfma16(af[j][ks], bfH[n][ks], acc[MFH + j][2 + n]); \
    __builtin_amdgcn_s_setprio(0);                                                \
    asm volatile("s_waitcnt vmcnt(4)" ::: "memory"); /* A(t+1)+B(t+1) landed */   \
    SBAR();                                                                       \
  }

  for (int tt = 0; tt < T; tt += 2) {  // T even for all shapes (32, 88)
    TILE_BODY(tt, 0);
    TILE_BODY(tt + 1, 1);
  }
#undef TILE_BODY
#undef STAGE_A
#undef STAGE_B

  const bool do_rope = ROPE && (n0 < 4096);
#pragma unroll
  for (int mf = 0; mf < MF; ++mf)
#pragma unroll
    for (int nf = 0; nf < 4; ++nf)
#pragma unroll
      for (int j = 0; j < 4; ++j) {
        const int rr = m0 + wm * (MF * 16) + mf * 16 + kc * 4 + j;
        const int cc = n0 + wn * 64 + nf * 16 + r;
        float v = acc[mf][nf][j];
        if (OM == 0) {
          if (ROPE) {  // fused RoPE: lanes r, r^1 hold (re,im) of one pair
            const float partner = __shfl_xor(v, 1);
            if (do_rope) {
              const int s = rr & (SQ - 1);
              const int i0 = (cc >> 1) & 63;
              const float cv = fc[s * 64 + i0];
              const float sv = fs[s * 64 + i0];
              v = ((r & 1) == 0) ? v * cv - partner * sv : v * cv + partner * sv;
            }
          }
          Cb[(size_t)rr * N + cc] = f2bf(v);
        } else {
          Cf[(size_t)rr * N + cc] = v + resid[(size_t)rr * N + cc];
        }
      }
}

// ============================================================================
// Fused FFN GEMM, faithful m201 8-phase schedule.
// act[4096][5632] = silu(f_in@w1) * (f_in@w3), bf16 out.
// Per K-tile: 4 phases x 16 MFMA (G01,G23,U01,U23), each phase:
//   {stage ONE half-tile + ds_read subtile} -> s_barrier -> lgkmcnt(0) ->
//   setprio(1) 16xMFMA setprio(0) -> s_barrier
// Stage stream: p0: B-up(t+1); p1: A-lo(t+2); p2: A-hi(t+2); p3: B-gate(t+2).
// vmcnt(6) once per tile at p3-end: drains through tile t+1's last half-tile
// (in-order), keeping 3 half-tiles (6 loads) in flight. Never vmcnt(0).
// ============================================================================
__global__ __launch_bounds__(512, 1) void gemm_ffn(const u16* __restrict__ A,
                                                   const u16* __restrict__ Bi,
                                                   u16* __restrict__ act) {
  __shared__ u16 lds[65536];  // A bufs @0,32768; B bufs @65536,98304 (bytes)
  const int tid = threadIdx.x, wid = tid >> 6, lane = tid & 63;
  const int wm = wid >> 1, wn = wid & 1;
  const int r = lane & 15, kc = lane >> 4;
  const int o = blockIdx.x;                 // 704 blocks = 16 m x 44 chunks
  const int seq = (o & 7) * 88 + (o >> 3);  // XCD-chunked, row-major
  const int by = seq / 44, bx = seq - by * 44;
  const int m0 = by << 8;
  const int T = 32;  // K = 2048

  const u16* Ag = A + (size_t)m0 * DIMQ;
  const u16* Bg = Bi + (size_t)bx * 256 * DIMQ;

  const int pl = (tid * 16) ^ (((tid >> 3) & 7) << 4);
  const int prow = pl >> 7, pcol = (pl & 127) >> 1;
  const int rd0 = r * 128 + ((kc * 16) ^ ((r & 7) << 4));
  const int waveA = wm * 8192;  // 64 rows
  const int waveB = wn * 8192;  // 64 gate rows (up at +16384)

  f32x4 accG[4][4] = {}, accU[4][4] = {};
  s16x8 af[4][2], bL[2][2], bH[2][2];

#define STG(G, kt, BUFB, h)                                                       \
  {                                                                               \
    _Pragma("unroll") for (int i = 0; i < 2; ++i)                                 \
        gl_lds16(G + (size_t)((h) * 128 + i * 64 + prow) * DIMQ + (kt) * 64 + pcol,\
                 (char*)lds + (BUFB) + (h) * 16384 + i * 8192 + (wid << 10));     \
  }

  // prologue (steady-state stream order): tile0 {A-lo,A-hi,B-gate,B-up} -> buf0;
  // tile1 {A-lo,A-hi,B-gate} -> buf1. vmcnt(6): tile0 fully landed, tile1's
  // 3 halves in flight. B-up(1) staged at tile0's p0.
  STG(Ag, 0, 0, 0);
  STG(Ag, 0, 0, 1);
  STG(Bg, 0, 65536, 0);
  STG(Bg, 0, 65536, 1);
  STG(Ag, 1, 32768, 0);
  STG(Ag, 1, 32768, 1);
  STG(Bg, 1, 98304, 0);
  asm volatile("s_waitcnt vmcnt(6)" ::: "memory");
  SBAR();

#define FFN_BODY(t, cur)                                                          \
  {                                                                               \
    const int tp1 = ((t) + 1 < T) ? (t) + 1 : T - 1;                              \
    const int tp2 = ((t) + 2 < T) ? (t) + 2 : T - 1;                              \
    const int AB = (cur)*32768;                                                   \
    const int BB = 65536 + (cur)*32768;                                           \
    const int BBn = 65536 + (1 - (cur)) * 32768;                                  \
    /* ==== p0: stage B-up(t+1); read af(8) + gate-lo(4); mfma G01 ==== */        \
    STG(Bg, tp1, BBn, 1);                                                         \
    _Pragma("unroll") for (int j = 0; j < 4; ++j)                                 \
        _Pragma("unroll") for (int ks = 0; ks < 2; ++ks)                          \
            af[j][ks] = *(const s16x8*)((const char*)lds + AB + waveA +           \
                                        j * 2048 + (rd0 ^ (ks << 6)));            \
    _Pragma("unroll") for (int n = 0; n < 2; ++n)                                 \
        _Pragma("unroll") for (int ks = 0; ks < 2; ++ks)                          \
            bL[n][ks] = *(const s16x8*)((const char*)lds + BB + waveB +           \
                                        n * 2048 + (rd0 ^ (ks << 6)));            \
    SBAR();                                                                       \
    LGKM0();                                                                      \
    __builtin_amdgcn_s_setprio(1);                                                \
    _Pragma("unroll") for (int ks = 0; ks < 2; ++ks)                              \
        _Pragma("unroll") for (int j = 0; j < 4; ++j)                             \
            _Pragma("unroll") for (int n = 0; n < 2; ++n)                         \
                accG[j][n] = mfma16(af[j][ks], bL[n][ks], accG[j][n]);            \
    __builtin_amdgcn_s_setprio(0);                                                \
    SBAR();                                                                       \
    /* ==== p1: stage A-lo(t+2); read gate-hi(4); mfma G23 ==== */                \
    STG(Ag, tp2, AB, 0);                                                          \
    _Pragma("unroll") for (int n = 0; n < 2; ++n)                                 \
        _Pragma("unroll") for (int ks = 0; ks < 2; ++ks)                          \
            bH[n][ks] = *(const s16x8*)((const char*)lds + BB + waveB +           \
                                        (2 + n) * 2048 + (rd0 ^ (ks << 6)));      \
    SBAR();                                                                       \
    LGKM0();                                                                      \
    __builtin_amdgcn_s_setprio(1);                                                \
    _Pragma("unroll") for (int ks = 0; ks < 2; ++ks)                              \
        _Pragma("unroll") for (int j = 0; j < 4; ++j)                             \
            _Pragma("unroll") for (int n = 0; n < 2; ++n)                         \
                accG[j][2 + n] = mfma16(af[j][ks], bH[n][ks], accG[j][2 + n]);    \
    __builtin_amdgcn_s_setprio(0);                                                \
    SBAR();                                                                       \
    /* ==== p2: stage A-hi(t+2); read up-lo(4); mfma U01 ==== */                  \
    STG(Ag, tp2, AB, 1);                                                          \
    _Pragma("unroll") for (int n = 0; n < 2; ++n)                                 \
        _Pragma("unroll") for (int ks = 0; ks < 2; ++ks)                          \
            bL[n][ks] = *(const s16x8*)((const char*)lds + BB + 16384 + waveB +   \
                                        n * 2048 + (rd0 ^ (ks << 6)));            \
    SBAR();                                                                       \
    LGKM0();                                                                      \
    __builtin_amdgcn_s_setprio(1);                                                \
    _Pragma("unroll") for (int ks = 0; ks < 2; ++ks)                              \
        _Pragma("unroll") for (int j = 0; j < 4; ++j)                             \
            _Pragma("unroll") for (int n = 0; n < 2; ++n)                         \
                accU[j][n] = mfma16(af[j][ks], bL[n][ks], accU[j][n]);            \
    __builtin_amdgcn_s_setprio(0);                                                \
    SBAR();                                                                       \
    /* ==== p3: stage B-gate(t+2); read up-hi(4); mfma U23; vmcnt(6) ==== */      \
    STG(Bg, tp2, BB, 0);                                                          \
    _Pragma("unroll") for (int n = 0; n < 2; ++n)                                 \
        _Pragma("unroll") for (int ks = 0; ks < 2; ++ks)                          \
            bH[n][ks] = *(const s16x8*)((const char*)lds + BB + 16384 + waveB +   \
                                        (2 + n) * 2048 + (rd0 ^ (ks << 6)));      \
    SBAR();                                                                       \
    LGKM0();                                                                      \
    __builtin_amdgcn_s_setprio(1);                                                \
    _Pragma("unroll") for (int ks = 0; ks < 2; ++ks)                              \
        _Pragma("unroll") for (int j = 0; j < 4; ++j)                             \
            _Pragma("unroll") for (int n = 0; n < 2; ++n)                         \
                accU[j][2 + n] = mfma16(af[j][ks], bH[n][ks], accU[j][2 + n]);    \
    __builtin_amdgcn_s_setprio(0);                                                \
    asm volatile("s_waitcnt vmcnt(6)" ::: "memory"); /* tile t+1 fully landed */  \
    SBAR();                                                                       \
  }

  for (int tt = 0; tt < T; tt += 2) {
    FFN_BODY(tt, 0);
    FFN_BODY(tt + 1, 1);
  }
#undef FFN_BODY
#undef STG

  const int cbase = bx * 128 + wn * 64;
#pragma unroll
  for (int mf = 0; mf < 4; ++mf)
#pragma unroll
    for (int nf = 0; nf < 4; ++nf)
#pragma unroll
      for (int j = 0; j < 4; ++j) {
        const int rr = m0 + wm * 64 + mf * 16 + kc * 4 + j;
        const int cc = cbase + nf * 16 + r;
        const float g = accG[mf][nf][j];
        const float u = accU[mf][nf][j];
        const float a = g / (1.f + __expf(-g)) * u;
        act[(size_t)rr * HIDQ + cc] = f2bf(a);
      }
}

// ============================================================================
// Causal flash attention, diagonal-paired for uniform makespan.
// ============================================================================
__global__ __launch_bounds__(512) void attn_k(const u16* __restrict__ qkv,
                                              const u16* __restrict__ vt,
                                              u16* __restrict__ outb) {
  __shared__ u16 Kl[64 * 136];      // [key][d], stride 136
  __shared__ u16 Vl[128 * 72];      // [d][key], stride 72
  __shared__ u16 Pl[8][16 * 80];    // per-wave P tile [qrow][key]
  const int bh = blockIdx.x;
  const int pr = blockIdx.y;         // 0..15
  const int b = bh >> 4, h = bh & 15;
  const int tid = threadIdx.x, wid = tid >> 6, lane = tid & 63;
  const int r = lane & 15, kc = lane >> 4;
  const int nt_lo = pr + 1, nt = 32 - pr;
  const int qbase = ((wid < 4) ? pr * 64 : (31 - pr) * 64) + (wid & 3) * 16;
  const size_t base = (size_t)b * SQ * 6144;
  const u16* vtb = vt + (size_t)bh * HDQ * SQ;
  s16x8 qf[4];
  {
    const size_t qoff = base + (size_t)(qbase + r) * 6144 + h * HDQ;
#pragma unroll
    for (int kk = 0; kk < 4; ++kk)
      qf[kk] = *(const s16x8*)&qkv[qoff + kk * 32 + kc * 8];
  }
  f32x4 acc_o[8] = {};
  float m_run[4], l_run[4];
#pragma unroll
  for (int j = 0; j < 4; ++j) { m_run[j] = -1e30f; l_run[j] = 0.f; }
  // staging indices (512 threads)
  const int kr = tid >> 4, kc8 = (tid & 15) * 8;   // K: rows kr, kr+32; 128 elems
  const int vr = tid >> 3, vc8 = (tid & 7) * 8;    // V: rows vr, vr+64; 64 elems
  const u16* kgp = &qkv[base + (size_t)kr * 6144 + 2048 + h * HDQ + kc8];
  const u16* vgp = &vtb[(size_t)vr * SQ + vc8];
  s16x8 kreg[2], vreg[2];
  kreg[0] = *(const s16x8*)kgp;
  kreg[1] = *(const s16x8*)(kgp + (size_t)32 * 6144);
  vreg[0] = *(const s16x8*)vgp;
  vreg[1] = *(const s16x8*)(vgp + (size_t)64 * SQ);
  for (int t = 0; t < nt; ++t) {
    const int kv0 = t * 64;
    __syncthreads();  // previous tile's LDS reads done
    *(s16x8*)&Kl[kr * 136 + kc8] = kreg[0];
    *(s16x8*)&Kl[(kr + 32) * 136 + kc8] = kreg[1];
    *(s16x8*)&Vl[vr * 72 + vc8] = vreg[0];
    *(s16x8*)&Vl[(vr + 64) * 72 + vc8] = vreg[1];
    __syncthreads();
    if (t + 1 < nt) {  // issue next tile's loads; land under compute (T14)
      const u16* kg = kgp + (size_t)(kv0 + 64) * 6144;
      const u16* vg = vgp + (kv0 + 64);
      kreg[0] = *(const s16x8*)kg;
      kreg[1] = *(const s16x8*)(kg + (size_t)32 * 6144);
      vreg[0] = *(const s16x8*)vg;
      vreg[1] = *(const s16x8*)(vg + (size_t)64 * SQ);
    }
    if (wid >= 4 || t < nt_lo) {
      // S = Q*K^T for this wave's 16 q-rows x 64 keys
      f32x4 sacc[4] = {};
      __builtin_amdgcn_s_setprio(1);
#pragma unroll
      for (int nf = 0; nf < 4; ++nf)
#pragma unroll
        for (int kk = 0; kk < 4; ++kk) {
          const s16x8 kf = *(const s16x8*)&Kl[(nf * 16 + r) * 136 + kk * 32 + kc * 8];
          sacc[nf] = mfma16(qf[kk], kf, sacc[nf]);
        }
      __builtin_amdgcn_s_setprio(0);
      // online softmax
      float p[4][4], alpha[4];
#pragma unroll
      for (int j = 0; j < 4; ++j) {
        const int qrow = qbase + kc * 4 + j;
        float svs[4];
        float tm = -1e30f;
#pragma unroll
        for (int nf = 0; nf < 4; ++nf) {
          const int key = kv0 + nf * 16 + r;
          float sv = sacc[nf][j] * SC_ATTN;
          sv = (key > qrow) ? -1e30f : sv;
          svs[nf] = sv;
          tm = fmaxf(tm, sv);
        }
        tm = fmaxf(tm, __shfl_xor(tm, 1));
        tm = fmaxf(tm, __shfl_xor(tm, 2));
        tm = fmaxf(tm, __shfl_xor(tm, 4));
        tm = fmaxf(tm, __shfl_xor(tm, 8));
        const float mnew = fmaxf(m_run[j], tm);
        alpha[j] = __expf(m_run[j] - mnew);
        m_run[j] = mnew;
        float rs = 0.f;
#pragma unroll
        for (int nf = 0; nf < 4; ++nf) {
          const float pv = __expf(svs[nf] - mnew);
          p[nf][j] = pv;
          rs += pv;
        }
        rs += __shfl_xor(rs, 1);
        rs += __shfl_xor(rs, 2);
        rs += __shfl_xor(rs, 4);
        rs += __shfl_xor(rs, 8);
        l_run[j] = l_run[j] * alpha[j] + rs;
      }
#pragma unroll
      for (int nf = 0; nf < 8; ++nf)
#pragma unroll
        for (int j = 0; j < 4; ++j)
          acc_o[nf][j] *= alpha[j];
      // P (D-layout) -> per-wave LDS -> A-layout fragments
#pragma unroll
      for (int nf = 0; nf < 4; ++nf)
#pragma unroll
        for (int j = 0; j < 4; ++j)
          Pl[wid][(kc * 4 + j) * 80 + nf * 16 + r] = f2bf(p[nf][j]);
      __builtin_amdgcn_s_setprio(1);
#pragma unroll
      for (int ks = 0; ks < 2; ++ks) {
        const s16x8 pa = *(const s16x8*)&Pl[wid][r * 80 + ks * 32 + kc * 8];
#pragma unroll
        for (int nf = 0; nf < 8; ++nf) {
          const s16x8 bv = *(const s16x8*)&Vl[(nf * 16 + r) * 72 + ks * 32 + kc * 8];
          acc_o[nf] = mfma16(pa, bv, acc_o[nf]);
        }
      }
      __builtin_amdgcn_s_setprio(0);
    }
  }
#pragma unroll
  for (int j = 0; j < 4; ++j) {
    const float inv = 1.0f / l_run[j];
    const size_t orow = (size_t)(b * SQ + qbase + kc * 4 + j) * DIMQ + h * HDQ;
#pragma unroll
    for (int nf = 0; nf < 8; ++nf)
      outb[orow + nf * 16 + r] = f2bf(acc_o[nf][j] * inv);
  }
}

extern "C" void kernel_launch(void* const* d_in, const int* in_sizes, int n_in,
                              void* d_out, int out_size, void* d_ws, size_t ws_size,
                              hipStream_t stream) {
  const float* x   = (const float*)d_in[0];
  const float* wq  = (const float*)d_in[1];
  const float* wk  = (const float*)d_in[2];
  const float* wv  = (const float*)d_in[3];
  const float* wo  = (const float*)d_in[4];
  const float* w1  = (const float*)d_in[5];
  const float* w2  = (const float*)d_in[6];  // note: w2 comes before w3 in dict order
  const float* w3  = (const float*)d_in[7];
  const float* anw = (const float*)d_in[8];
  const float* fnw = (const float*)d_in[9];
  const float* fc  = (const float*)d_in[10];
  const float* fs  = (const float*)d_in[11];
  float* out = (float*)d_out;

  char* ws = (char*)d_ws;
  // weights (bf16, transposed)
  u16* wqkvT = (u16*)(ws);                                  // [6144][2048]
  u16* woT   = (u16*)(ws + 25165824);                       // [2048][2048]
  u16* w13i  = (u16*)(ws + 25165824 + 8388608);             // [11264][2048] interleaved
  u16* w2T   = (u16*)(ws + 25165824 + 8388608 + 46137344);  // [2048][5632]
  // activations
  u16* hin   = (u16*)(ws + 102760448);                      // [4096][2048] bf16
  u16* qkvb  = (u16*)(ws + 119537664);                      // attn: [4096][6144]; FFN: act [4096][5632]
  u16* act   = qkvb;
  u16* attnb = (u16*)(ws + 119537664 + 50331648);           // [4096][2048] bf16
  u16* vtb   = (u16*)(ws + 119537664 + 50331648 + 16777216);// [32][128][2048] bf16
  float* h = out;                                           // h lives in d_out

  const dim3 tb(32, 8);
  transpose_cvt<<<dim3(64, 64), tb, 0, stream>>>(wq, wqkvT, 2048, 2048);
  transpose_cvt<<<dim3(64, 64), tb, 0, stream>>>(wk, wqkvT + (size_t)2048 * 2048, 2048, 2048);
  transpose_cvt<<<dim3(64, 64), tb, 0, stream>>>(wv, wqkvT + (size_t)2 * 2048 * 2048, 2048, 2048);
  transpose_cvt<<<dim3(64, 64), tb, 0, stream>>>(wo, woT, 2048, 2048);
  transpose_cvt_ffn<<<dim3(176, 64), tb, 0, stream>>>(w1, w13i, 0);
  transpose_cvt_ffn<<<dim3(176, 64), tb, 0, stream>>>(w3, w13i, 128);
  transpose_cvt<<<dim3(64, 176), tb, 0, stream>>>(w2, w2T, 5632, 2048);

  rmsnorm_k<<<4096, 256, 0, stream>>>(x, anw, hin);
  gemm256<0, 128, 1><<<768, 512, 0, stream>>>(hin, wqkvT, qkvb, nullptr, nullptr, fc, fs, 6144, 2048, 2048);
  vtrans_k<<<dim3(64, 4, 32), tb, 0, stream>>>(qkvb, vtb);
  attn_k<<<dim3(32, 16), 512, 0, stream>>>(qkvb, vtb, attnb);
  gemm256<1, 128, 0><<<256, 512, 0, stream>>>(attnb, woT, nullptr, h, x, nullptr, nullptr, 2048, 2048, 2048);
  rmsnorm_k<<<4096, 256, 0, stream>>>(h, fnw, hin);
  gemm_ffn<<<704, 512, 0, stream>>>(hin, w13i, act);
  gemm256<1, 128, 0><<<256, 512, 0, stream>>>(act, w2T, nullptr, out, h, nullptr, nullptr, 2048, 5632, 5632);
}

// Round 13
// 593.675 us; speedup vs baseline: 1.0941x; 1.0774x over previous
//
#include <hip/hip_runtime.h>

// ---- problem constants ----
#define DIMQ 2048
#define NHQ  16
#define HDQ  128
#define BQ   2
#define SQ   2048
#define HIDQ 5632
#define MQ   (BQ * SQ)   // 4096
#define SC_ATTN 0.08838834764831845f  // 1/sqrt(128)

using u16 = unsigned short;
using u32 = unsigned int;
typedef __attribute__((ext_vector_type(8))) short s16x8;
typedef __attribute__((ext_vector_type(4))) float f32x4;
typedef __attribute__((ext_vector_type(2))) u32 u32x2;

__device__ __forceinline__ float bf2f(u16 v) {
  union { u32 u; float f; } w; w.u = ((u32)v) << 16; return w.f;
}
__device__ __forceinline__ u16 f2bf(float f) {
  union { float f; u32 u; } w; w.f = f;
  u32 r = w.u + 0x7FFFu + ((w.u >> 16) & 1u);  // RNE
  return (u16)(r >> 16);
}
__device__ __forceinline__ u32 cvtpk_bf16(float a, float b) {
  u32 r;
  asm("v_cvt_pk_bf16_f32 %0, %1, %2" : "=v"(r) : "v"(a), "v"(b));
  return r;
}

__device__ __forceinline__ f32x4 mfma16(s16x8 a, s16x8 b, f32x4 c) {
  return __builtin_amdgcn_mfma_f32_16x16x32_bf16(a, b, c, 0, 0, 0);
}

// async global->LDS, 16B per lane; LDS dest is wave-uniform base + lane*16
__device__ __forceinline__ void gl_lds16(const void* g, void* l) {
  __builtin_amdgcn_global_load_lds((const __attribute__((address_space(1))) void*)g,
                                   (__attribute__((address_space(3))) void*)l,
                                   16, 0, 0);
}

#define SBAR()                                   \
  {                                              \
    asm volatile("" ::: "memory");               \
    __builtin_amdgcn_s_barrier();                \
    asm volatile("" ::: "memory");               \
  }
#define LGKM0() asm volatile("s_waitcnt lgkmcnt(0)" ::: "memory")

// ---- weight transpose + fp32->bf16 convert: src[R][Cn] f32 -> dst[Cn][R] bf16 ----
__global__ __launch_bounds__(256) void transpose_cvt(const float* __restrict__ src,
                                                     u16* __restrict__ dst,
                                                     int R, int Cn) {
  __shared__ float tile[32][33];
  const int tx = threadIdx.x, ty = threadIdx.y;
  const int c0 = blockIdx.x * 32, r0 = blockIdx.y * 32;
#pragma unroll
  for (int i = 0; i < 4; ++i)
    tile[ty + i * 8][tx] = src[(size_t)(r0 + ty + i * 8) * Cn + c0 + tx];
  __syncthreads();
#pragma unroll
  for (int i = 0; i < 4; ++i)
    dst[(size_t)(c0 + ty + i * 8) * R + r0 + tx] = f2bf(tile[tx][ty + i * 8]);
}

// ---- FFN weight transpose with gate/up interleave: src[2048][5632] f32 ->
// dst row' = (n>>7)*256 + base + (n&127). ----
__global__ __launch_bounds__(256) void transpose_cvt_ffn(const float* __restrict__ src,
                                                         u16* __restrict__ dst,
                                                         int base) {
  __shared__ float tile[32][33];
  const int tx = threadIdx.x, ty = threadIdx.y;
  const int c0 = blockIdx.x * 32, r0 = blockIdx.y * 32;  // c0 over 5632, r0 over 2048
#pragma unroll
  for (int i = 0; i < 4; ++i)
    tile[ty + i * 8][tx] = src[(size_t)(r0 + ty + i * 8) * HIDQ + c0 + tx];
  __syncthreads();
#pragma unroll
  for (int i = 0; i < 4; ++i) {
    const int n = c0 + ty + i * 8;
    const int row = (n >> 7) * 256 + base + (n & 127);
    dst[(size_t)row * DIMQ + r0 + tx] = f2bf(tile[tx][ty + i * 8]);
  }
}

// ---- V transpose: qkv v-slice [s][d] bf16 -> Vt[bh][d][s] bf16 ----
__global__ __launch_bounds__(256) void vtrans_k(const u16* __restrict__ qkv,
                                                u16* __restrict__ vt) {
  __shared__ u16 tile[32][33];
  const int bh = blockIdx.z;
  const int b = bh >> 4, h = bh & 15;
  const int s0 = blockIdx.x * 32, d0 = blockIdx.y * 32;
  const int tx = threadIdx.x, ty = threadIdx.y;
  const u16* src = qkv + (size_t)(b * SQ) * 6144 + 4096 + h * HDQ;
#pragma unroll
  for (int i = 0; i < 4; ++i)
    tile[ty + i * 8][tx] = src[(size_t)(s0 + ty + i * 8) * 6144 + d0 + tx];
  __syncthreads();
  u16* dst = vt + (size_t)bh * HDQ * SQ;
#pragma unroll
  for (int i = 0; i < 4; ++i)
    dst[(size_t)(d0 + ty + i * 8) * SQ + s0 + tx] = tile[tx][ty + i * 8];
}

// ---- RMSNorm: f32 [rows][2048] -> bf16, one block per row ----
__global__ __launch_bounds__(256) void rmsnorm_k(const float* __restrict__ x,
                                                 const float* __restrict__ w,
                                                 u16* __restrict__ o) {
  const int row = blockIdx.x;
  const int t = threadIdx.x;
  const float* xr = x + (size_t)row * DIMQ;
  const float4 a = ((const float4*)xr)[t * 2];
  const float4 b = ((const float4*)xr)[t * 2 + 1];
  float ss = a.x * a.x + a.y * a.y + a.z * a.z + a.w * a.w +
             b.x * b.x + b.y * b.y + b.z * b.z + b.w * b.w;
#pragma unroll
  for (int off = 32; off > 0; off >>= 1) ss += __shfl_down(ss, off);
  __shared__ float red[4];
  if ((t & 63) == 0) red[t >> 6] = ss;
  __syncthreads();
  ss = red[0] + red[1] + red[2] + red[3];
  const float rs = rsqrtf(ss * (1.0f / (float)DIMQ) + 1e-6f);
  const float4 wa = ((const float4*)w)[t * 2];
  const float4 wb = ((const float4*)w)[t * 2 + 1];
  s16x8 ov;
  ov[0] = (short)f2bf(a.x * rs * wa.x);
  ov[1] = (short)f2bf(a.y * rs * wa.y);
  ov[2] = (short)f2bf(a.z * rs * wa.z);
  ov[3] = (short)f2bf(a.w * rs * wa.w);
  ov[4] = (short)f2bf(b.x * rs * wb.x);
  ov[5] = (short)f2bf(b.y * rs * wb.y);
  ov[6] = (short)f2bf(b.z * rs * wb.z);
  ov[7] = (short)f2bf(b.w * rs * wb.w);
  *(s16x8*)(o + (size_t)row * DIMQ + t * 8) = ov;
}

// ============================================================================
// 256xBN tile GEMM, BK=64, 8 waves, round-6 free-form 4-phase body (633us
// baseline): B(t+1) staged ph0/ph1, A(t+2) staged ph3, counted vmcnt(4).
// ============================================================================
template <int OM, int BN, int ROPE>
__global__ __launch_bounds__(512, 1) void gemm256(const u16* __restrict__ A,
                                                  const u16* __restrict__ Bt,
                                                  u16* __restrict__ Cb,
                                                  float* __restrict__ Cf,
                                                  const float* __restrict__ resid,
                                                  const float* __restrict__ fc,
                                                  const float* __restrict__ fs,
                                                  int N, int K, int lda) {
  constexpr int BT = BN * 128;             // B K-tile bytes
  constexpr int BLB = BN / 128;            // gl_lds per thread per B half
  constexpr int WNv = (BN == 256) ? 4 : 2; // waves along N
  constexpr int MF = (BN == 256) ? 8 : 4;  // 16-row A frags per wave
  constexpr int MFH = MF / 2;
  __shared__ u16 lds[(65536 + 2 * BT) / 2];  // A: 0,32768; B: 65536, 65536+BT
  const int tid = threadIdx.x, wid = tid >> 6, lane = tid & 63;
  const int wm = wid / WNv, wn = wid % WNv;
  const int r = lane & 15, kc = lane >> 4;
  const int nbx = N / BN;
  const int nwg = nbx << 4;
  const int o = blockIdx.x;
  const int seq = (o & 7) * (nwg >> 3) + (o >> 3);  // XCD-chunked, row-major
  const int by = seq / nbx, bx = seq - by * nbx;
  const int m0 = by << 8, n0 = bx * BN;
  const int T = K >> 6;

  const u16* Ag = A + (size_t)m0 * lda;
  const u16* Bg = Bt + (size_t)n0 * K;

  // staging source swizzle (involution byte^=((byte>>7&7)<<4); linear LDS dest)
  const int pl = (tid * 16) ^ (((tid >> 3) & 7) << 4);
  const int prow = pl >> 7;           // = tid>>3, 0..63
  const int pcol = (pl & 127) >> 1;   // element offset within 64-elem row

  // read-side swizzled base: row r, k-chunk kc (XOR ks<<6 per k-slice)
  const int rd0 = r * 128 + ((kc * 16) ^ ((r & 7) << 4));
  const int waveA = wm * (MF * 2048);
  const int waveB = wn * 8192;

  f32x4 acc[MF][4] = {};
  s16x8 af[MFH][2], bfL[2][2], bfH[2][2];

#define STAGE_A(G, kt, BUFB, h)                                                   \
  {                                                                               \
    _Pragma("unroll") for (int i = 0; i < 2; ++i)                                 \
        gl_lds16(G + (size_t)((h) * 128 + i * 64 + prow) * lda + (kt) * 64 + pcol,\
                 (char*)lds + (BUFB) + (h) * 16384 + i * 8192 + (wid << 10));     \
  }
#define STAGE_B(G, kt, BUFB, h)                                                   \
  {                                                                               \
    _Pragma("unroll") for (int i = 0; i < BLB; ++i)                               \
        gl_lds16(G + (size_t)((h) * (BN / 2) + i * 64 + prow) * K + (kt) * 64 + pcol, \
                 (char*)lds + (BUFB) + (h) * (BT / 2) + i * 8192 + (wid << 10));  \
  }

  // prologue: tile0 A+B -> buf0; tile1 A -> buf1
  STAGE_A(Ag, 0, 0, 0);
  STAGE_A(Ag, 0, 0, 1);
  STAGE_B(Bg, 0, 65536, 0);
  STAGE_B(Bg, 0, 65536, 1);
  STAGE_A(Ag, 1, 32768, 0);
  STAGE_A(Ag, 1, 32768, 1);
  asm volatile("s_waitcnt vmcnt(4)" ::: "memory");
  SBAR();

#define TILE_BODY(t, cur)                                                         \
  {                                                                               \
    const int tp1 = ((t) + 1 < T) ? (t) + 1 : T - 1;                              \
    const int tp2 = ((t) + 2 < T) ? (t) + 2 : T - 1;                              \
    const int AB = (cur)*32768;                                                   \
    const int BB = 65536 + (cur)*BT;                                              \
    const int BBn = 65536 + (1 - (cur)) * BT;                                     \
    /* ---- phase 0: stage B.h0(t+1); read A(lo)+B(lo); mfma Q(0,0) ---- */       \
    STAGE_B(Bg, tp1, BBn, 0);                                                     \
    _Pragma("unroll") for (int j = 0; j < MFH; ++j)                               \
        _Pragma("unroll") for (int ks = 0; ks < 2; ++ks)                          \
            af[j][ks] = *(const s16x8*)((const char*)lds + AB + waveA +           \
                                        j * 2048 + (rd0 ^ (ks << 6)));            \
    _Pragma("unroll") for (int n = 0; n < 2; ++n)                                 \
        _Pragma("unroll") for (int ks = 0; ks < 2; ++ks)                          \
            bfL[n][ks] = *(const s16x8*)((const char*)lds + BB + waveB +          \
                                         n * 2048 + (rd0 ^ (ks << 6)));           \
    __builtin_amdgcn_s_setprio(1);                                                \
    _Pragma("unroll") for (int ks = 0; ks < 2; ++ks)                              \
        _Pragma("unroll") for (int j = 0; j < MFH; ++j)                           \
            _Pragma("unroll") for (int n = 0; n < 2; ++n)                         \
                acc[j][n] = mfma16(af[j][ks], bfL[n][ks], acc[j][n]);             \
    __builtin_amdgcn_s_setprio(0);                                                \
    /* ---- phase 1: stage B.h1(t+1); read B(hi); mfma Q(0,1) ---- */             \
    STAGE_B(Bg, tp1, BBn, 1);                                                     \
    _Pragma("unroll") for (int n = 0; n < 2; ++n)                                 \
        _Pragma("unroll") for (int ks = 0; ks < 2; ++ks)                          \
            bfH[n][ks] = *(const s16x8*)((const char*)lds + BB + waveB +          \
                                         (2 + n) * 2048 + (rd0 ^ (ks << 6)));     \
    __builtin_amdgcn_s_setprio(1);                                                \
    _Pragma("unroll") for (int ks = 0; ks < 2; ++ks)                              \
        _Pragma("unroll") for (int j = 0; j < MFH; ++j)                           \
            _Pragma("unroll") for (int n = 0; n < 2; ++n)                         \
                acc[j][2 + n] = mfma16(af[j][ks], bfH[n][ks], acc[j][2 + n]);     \
    __builtin_amdgcn_s_setprio(0);                                                \
    /* ---- phase 2: read A(hi); mfma Q(1,0) ---- */                              \
    _Pragma("unroll") for (int j = 0; j < MFH; ++j)                               \
        _Pragma("unroll") for (int ks = 0; ks < 2; ++ks)                          \
            af[j][ks] = *(const s16x8*)((const char*)lds + AB + waveA +           \
                                        (MFH + j) * 2048 + (rd0 ^ (ks << 6)));    \
    __builtin_amdgcn_s_setprio(1);                                                \
    _Pragma("unroll") for (int ks = 0; ks < 2; ++ks)                              \
        _Pragma("unroll") for (int j = 0; j < MFH; ++j)                           \
            _Pragma("unroll") for (int n = 0; n < 2; ++n)                         \
                acc[MFH + j][n] = mfma16(af[j][ks], bfL[n][ks], acc[MFH + j][n]); \
    __builtin_amdgcn_s_setprio(0);                                                \
    SBAR(); /* all reads of buf[cur] done -> safe to overwrite its A region */    \
    /* ---- phase 3: stage A(t+2) into buf[cur]; mfma Q(1,1) ---- */              \
    STAGE_A(Ag, tp2, AB, 0);                                                      \
    STAGE_A(Ag, tp2, AB, 1);                                                      \
    __builtin_amdgcn_s_setprio(1);                                                \
    _Pragma("unroll") for (int ks = 0; ks < 2; ++ks)                              \
        _Pragma("unroll") for (int j = 0; j < MFH; ++j)                           \
            _Pragma("unroll") for (int n = 0; n < 2; ++n)                         \
                acc[MFH + j][2 + n] = mfma16(af[j][ks], bfH[n][ks], acc[MFH + j][2 + n]); \
    __builtin_amdgcn_s_setprio(0);                                                \
    asm volatile("s_waitcnt vmcnt(4)" ::: "memory"); /* A(t+1)+B(t+1) landed */   \
    SBAR();                                                                       \
  }

  for (int tt = 0; tt < T; tt += 2) {  // T even for all shapes (32, 88)
    TILE_BODY(tt, 0);
    TILE_BODY(tt + 1, 1);
  }
#undef TILE_BODY
#undef STAGE_A
#undef STAGE_B

  const bool do_rope = ROPE && (n0 < 4096);
#pragma unroll
  for (int mf = 0; mf < MF; ++mf)
#pragma unroll
    for (int nf = 0; nf < 4; ++nf)
#pragma unroll
      for (int j = 0; j < 4; ++j) {
        const int rr = m0 + wm * (MF * 16) + mf * 16 + kc * 4 + j;
        const int cc = n0 + wn * 64 + nf * 16 + r;
        float v = acc[mf][nf][j];
        if (OM == 0) {
          if (ROPE) {  // fused RoPE: lanes r, r^1 hold (re,im) of one pair
            const float partner = __shfl_xor(v, 1);
            if (do_rope) {
              const int s = rr & (SQ - 1);
              const int i0 = (cc >> 1) & 63;
              const float cv = fc[s * 64 + i0];
              const float sv = fs[s * 64 + i0];
              v = ((r & 1) == 0) ? v * cv - partner * sv : v * cv + partner * sv;
            }
          }
          Cb[(size_t)rr * N + cc] = f2bf(v);
        } else {
          Cf[(size_t)rr * N + cc] = v + resid[(size_t)rr * N + cc];
        }
      }
}

// ============================================================================
// Fused FFN GEMM (round-6 free-form body): act = silu(f_in@w1)*(f_in@w3).
// ============================================================================
__global__ __launch_bounds__(512, 1) void gemm_ffn(const u16* __restrict__ A,
                                                   const u16* __restrict__ Bi,
                                                   u16* __restrict__ act) {
  __shared__ u16 lds[65536];  // A bufs @0,32768; B bufs @65536,98304 (bytes)
  const int tid = threadIdx.x, wid = tid >> 6, lane = tid & 63;
  const int wm = wid >> 1, wn = wid & 1;
  const int r = lane & 15, kc = lane >> 4;
  const int o = blockIdx.x;                 // 704 blocks = 16 m x 44 chunks
  const int seq = (o & 7) * 88 + (o >> 3);  // XCD-chunked, row-major
  const int by = seq / 44, bx = seq - by * 44;
  const int m0 = by << 8;
  const int T = 32;  // K = 2048

  const u16* Ag = A + (size_t)m0 * DIMQ;
  const u16* Bg = Bi + (size_t)bx * 256 * DIMQ;

  const int pl = (tid * 16) ^ (((tid >> 3) & 7) << 4);
  const int prow = pl >> 7, pcol = (pl & 127) >> 1;
  const int rd0 = r * 128 + ((kc * 16) ^ ((r & 7) << 4));
  const int waveA = wm * 8192;  // 64 rows
  const int waveB = wn * 8192;  // 64 gate rows (up at +16384)

  f32x4 accG[4][4] = {}, accU[4][4] = {};
  s16x8 af[4][2], bL[2][2], bH[2][2];

#define STG(G, kt, BUFB, h)                                                       \
  {                                                                               \
    _Pragma("unroll") for (int i = 0; i < 2; ++i)                                 \
        gl_lds16(G + (size_t)((h) * 128 + i * 64 + prow) * DIMQ + (kt) * 64 + pcol,\
                 (char*)lds + (BUFB) + (h) * 16384 + i * 8192 + (wid << 10));     \
  }

  STG(Ag, 0, 0, 0);
  STG(Ag, 0, 0, 1);
  STG(Bg, 0, 65536, 0);
  STG(Bg, 0, 65536, 1);
  STG(Ag, 1, 32768, 0);
  STG(Ag, 1, 32768, 1);
  asm volatile("s_waitcnt vmcnt(4)" ::: "memory");
  SBAR();

#define FFN_BODY(t, cur)                                                          \
  {                                                                               \
    const int tp1 = ((t) + 1 < T) ? (t) + 1 : T - 1;                              \
    const int tp2 = ((t) + 2 < T) ? (t) + 2 : T - 1;                              \
    const int AB = (cur)*32768;                                                   \
    const int BB = 65536 + (cur)*32768;                                           \
    const int BBn = 65536 + (1 - (cur)) * 32768;                                  \
    /* ph0: stage B.h0(t+1); read af + gate01; mfma G01 */                        \
    STG(Bg, tp1, BBn, 0);                                                         \
    _Pragma("unroll") for (int j = 0; j < 4; ++j)                                 \
        _Pragma("unroll") for (int ks = 0; ks < 2; ++ks)                          \
            af[j][ks] = *(const s16x8*)((const char*)lds + AB + waveA +           \
                                        j * 2048 + (rd0 ^ (ks << 6)));            \
    _Pragma("unroll") for (int n = 0; n < 2; ++n)                                 \
        _Pragma("unroll") for (int ks = 0; ks < 2; ++ks)                          \
            bL[n][ks] = *(const s16x8*)((const char*)lds + BB + waveB +           \
                                        n * 2048 + (rd0 ^ (ks << 6)));            \
    __builtin_amdgcn_s_setprio(1);                                                \
    _Pragma("unroll") for (int ks = 0; ks < 2; ++ks)                              \
        _Pragma("unroll") for (int j = 0; j < 4; ++j)                             \
            _Pragma("unroll") for (int n = 0; n < 2; ++n)                         \
                accG[j][n] = mfma16(af[j][ks], bL[n][ks], accG[j][n]);            \
    __builtin_amdgcn_s_setprio(0);                                                \
    /* ph1: stage B.h1(t+1); read gate23; mfma G23 */                             \
    STG(Bg, tp1, BBn, 1);                                                         \
    _Pragma("unroll") for (int n = 0; n < 2; ++n)                                 \
        _Pragma("unroll") for (int ks = 0; ks < 2; ++ks)                          \
            bH[n][ks] = *(const s16x8*)((const char*)lds + BB + waveB +           \
                                        (2 + n) * 2048 + (rd0 ^ (ks << 6)));      \
    __builtin_amdgcn_s_setprio(1);                                                \
    _Pragma("unroll") for (int ks = 0; ks < 2; ++ks)                              \
        _Pragma("unroll") for (int j = 0; j < 4; ++j)                             \
            _Pragma("unroll") for (int n = 0; n < 2; ++n)                         \
                accG[j][2 + n] = mfma16(af[j][ks], bH[n][ks], accG[j][2 + n]);    \
    __builtin_amdgcn_s_setprio(0);                                                \
    /* ph2: read up01; mfma U01 */                                                \
    _Pragma("unroll") for (int n = 0; n < 2; ++n)                                 \
        _Pragma("unroll") for (int ks = 0; ks < 2; ++ks)                          \
            bL[n][ks] = *(const s16x8*)((const char*)lds + BB + 16384 + waveB +   \
                                        n * 2048 + (rd0 ^ (ks << 6)));            \
    __builtin_amdgcn_s_setprio(1);                                                \
    _Pragma("unroll") for (int ks = 0; ks < 2; ++ks)                              \
        _Pragma("unroll") for (int j = 0; j < 4; ++j)                             \
            _Pragma("unroll") for (int n = 0; n < 2; ++n)                         \
                accU[j][n] = mfma16(af[j][ks], bL[n][ks], accU[j][n]);            \
    __builtin_amdgcn_s_setprio(0);                                                \
    /* ph2b: read up23 (B-buf: not touched by STAGE_A, may cross barrier) */      \
    _Pragma("unroll") for (int n = 0; n < 2; ++n)                                 \
        _Pragma("unroll") for (int ks = 0; ks < 2; ++ks)                          \
            bH[n][ks] = *(const s16x8*)((const char*)lds + BB + 16384 + waveB +   \
                                        (2 + n) * 2048 + (rd0 ^ (ks << 6)));      \
    SBAR(); /* all A-buf reads done -> safe to overwrite */                       \
    /* ph3: stage A(t+2); mfma U23 */                                             \
    STG(Ag, tp2, AB, 0);                                                          \
    STG(Ag, tp2, AB, 1);                                                          \
    __builtin_amdgcn_s_setprio(1);                                                \
    _Pragma("unroll") for (int ks = 0; ks < 2; ++ks)                              \
        _Pragma("unroll") for (int j = 0; j < 4; ++j)                             \
            _Pragma("unroll") for (int n = 0; n < 2; ++n)                         \
                accU[j][2 + n] = mfma16(af[j][ks], bH[n][ks], accU[j][2 + n]);    \
    __builtin_amdgcn_s_setprio(0);                                                \
    asm volatile("s_waitcnt vmcnt(4)" ::: "memory");                              \
    SBAR();                                                                       \
  }

  for (int tt = 0; tt < T; tt += 2) {
    FFN_BODY(tt, 0);
    FFN_BODY(tt + 1, 1);
  }
#undef FFN_BODY
#undef STG

  const int cbase = bx * 128 + wn * 64;
#pragma unroll
  for (int mf = 0; mf < 4; ++mf)
#pragma unroll
    for (int nf = 0; nf < 4; ++nf)
#pragma unroll
      for (int j = 0; j < 4; ++j) {
        const int rr = m0 + wm * 64 + mf * 16 + kc * 4 + j;
        const int cc = cbase + nf * 16 + r;
        const float g = accG[mf][nf][j];
        const float u = accU[mf][nf][j];
        const float a = g / (1.f + __expf(-g)) * u;
        act[(size_t)rr * HIDQ + cc] = f2bf(a);
      }
}

// ============================================================================
// Causal flash attention, diagonal-paired; SWAPPED QK^T softmax:
// st = mfma(K, Q) puts S[qrow=lane&15][16 keys] lane-local -> row reduce is
// 15 serial ops + 2 shfl_xor(16,32). Defer-max (THR=8, log2 domain), exp2
// with SC*log2e folded into Q, cvt_pk_bf16 P-packing (4x 8B LDS writes).
// ============================================================================
__global__ __launch_bounds__(512) void attn_k(const u16* __restrict__ qkv,
                                              const u16* __restrict__ vt,
                                              u16* __restrict__ outb) {
  __shared__ u16 Kl[64 * 136];      // [key][d], stride 136
  __shared__ u16 Vl[128 * 72];      // [d][key], stride 72
  __shared__ u16 Pl[8][16 * 80];    // per-wave P tile [qrow][key]
  const int bh = blockIdx.x;
  const int pr = blockIdx.y;         // 0..15
  const int b = bh >> 4, h = bh & 15;
  const int tid = threadIdx.x, wid = tid >> 6, lane = tid & 63;
  const int r = lane & 15, kc = lane >> 4;
  const int nt_lo = pr + 1, nt = 32 - pr;
  const int qbase = ((wid < 4) ? pr * 64 : (31 - pr) * 64) + (wid & 3) * 16;
  const int qrow_r = qbase + r;      // this lane's softmax q-row
  const size_t base = (size_t)b * SQ * 6144;
  const u16* vtb = vt + (size_t)bh * HDQ * SQ;
  s16x8 qf[4];
  {
    const size_t qoff = base + (size_t)qrow_r * 6144 + h * HDQ;
    const float QSC = SC_ATTN * 1.44269504f;  // fold 1/sqrt(d) * log2(e)
#pragma unroll
    for (int kk = 0; kk < 4; ++kk) {
      s16x8 v = *(const s16x8*)&qkv[qoff + kk * 32 + kc * 8];
#pragma unroll
      for (int e = 0; e < 8; ++e) v[e] = (short)f2bf(bf2f((u16)v[e]) * QSC);
      qf[kk] = v;
    }
  }
  f32x4 acc_o[8] = {};
  float m_run = -1e30f, l_run = 0.f;
  // staging indices (512 threads)
  const int kr = tid >> 4, kc8 = (tid & 15) * 8;   // K: rows kr, kr+32; 128 elems
  const int vr = tid >> 3, vc8 = (tid & 7) * 8;    // V: rows vr, vr+64; 64 elems
  const u16* kgp = &qkv[base + (size_t)kr * 6144 + 2048 + h * HDQ + kc8];
  const u16* vgp = &vtb[(size_t)vr * SQ + vc8];
  s16x8 kreg[2], vreg[2];
  kreg[0] = *(const s16x8*)kgp;
  kreg[1] = *(const s16x8*)(kgp + (size_t)32 * 6144);
  vreg[0] = *(const s16x8*)vgp;
  vreg[1] = *(const s16x8*)(vgp + (size_t)64 * SQ);
  for (int t = 0; t < nt; ++t) {
    const int kv0 = t * 64;
    __syncthreads();  // previous tile's LDS reads done
    *(s16x8*)&Kl[kr * 136 + kc8] = kreg[0];
    *(s16x8*)&Kl[(kr + 32) * 136 + kc8] = kreg[1];
    *(s16x8*)&Vl[vr * 72 + vc8] = vreg[0];
    *(s16x8*)&Vl[(vr + 64) * 72 + vc8] = vreg[1];
    __syncthreads();
    if (t + 1 < nt) {  // issue next tile's loads; land under compute (T14)
      const u16* kg = kgp + (size_t)(kv0 + 64) * 6144;
      const u16* vg = vgp + (kv0 + 64);
      kreg[0] = *(const s16x8*)kg;
      kreg[1] = *(const s16x8*)(kg + (size_t)32 * 6144);
      vreg[0] = *(const s16x8*)vg;
      vreg[1] = *(const s16x8*)(vg + (size_t)64 * SQ);
    }
    if (wid >= 4 || t < nt_lo) {
      // S^T = K*Q^T: lane (r,kc) holds S[qrow=r][key = kv0 + nf*16 + kc*4 + j]
      f32x4 st[4] = {};
      __builtin_amdgcn_s_setprio(1);
#pragma unroll
      for (int nf = 0; nf < 4; ++nf)
#pragma unroll
        for (int kk = 0; kk < 4; ++kk) {
          const s16x8 kf = *(const s16x8*)&Kl[(nf * 16 + r) * 136 + kk * 32 + kc * 8];
          st[nf] = mfma16(kf, qf[kk], st[nf]);
        }
      __builtin_amdgcn_s_setprio(0);
      // masked per-lane max over this lane's 16 keys, then merge across kc
      float pv[16];
      float tm = -1e30f;
#pragma unroll
      for (int nf = 0; nf < 4; ++nf)
#pragma unroll
        for (int j = 0; j < 4; ++j) {
          const int key = kv0 + nf * 16 + kc * 4 + j;
          float sv = st[nf][j];
          sv = (key > qrow_r) ? -1e30f : sv;
          pv[nf * 4 + j] = sv;
          tm = fmaxf(tm, sv);
        }
      tm = fmaxf(tm, __shfl_xor(tm, 16));
      tm = fmaxf(tm, __shfl_xor(tm, 32));
      // defer-max: rescale only if some row's max grew past THR=8 (log2 units)
      if (__any(tm > m_run + 8.f)) {
        const float mnew = fmaxf(m_run, tm);
        const float alpha = exp2f(m_run - mnew);
        m_run = mnew;
        l_run *= alpha;
#pragma unroll
        for (int j = 0; j < 4; ++j) {
          const float aj = __shfl(alpha, kc * 4 + j);  // alpha of qrow kc*4+j
#pragma unroll
          for (int nf = 0; nf < 8; ++nf) acc_o[nf][j] *= aj;
        }
      }
      float rs = 0.f;
      u32 pk0[4], pk1[4];
#pragma unroll
      for (int nf = 0; nf < 4; ++nf) {
        const float p0 = exp2f(pv[nf * 4 + 0] - m_run);
        const float p1 = exp2f(pv[nf * 4 + 1] - m_run);
        const float p2 = exp2f(pv[nf * 4 + 2] - m_run);
        const float p3 = exp2f(pv[nf * 4 + 3] - m_run);
        rs += (p0 + p1) + (p2 + p3);
        pk0[nf] = cvtpk_bf16(p0, p1);
        pk1[nf] = cvtpk_bf16(p2, p3);
      }
      rs += __shfl_xor(rs, 16);
      rs += __shfl_xor(rs, 32);
      l_run += rs;
      // write P: lane (r,kc) owns keys nf*16 + kc*4 + [0,4) of row r
#pragma unroll
      for (int nf = 0; nf < 4; ++nf) {
        u32x2 w;
        w[0] = pk0[nf];
        w[1] = pk1[nf];
        *(u32x2*)&Pl[wid][r * 80 + nf * 16 + kc * 4] = w;
      }
      __builtin_amdgcn_s_setprio(1);
#pragma unroll
      for (int ks = 0; ks < 2; ++ks) {
        const s16x8 pa = *(const s16x8*)&Pl[wid][r * 80 + ks * 32 + kc * 8];
#pragma unroll
        for (int nf = 0; nf < 8; ++nf) {
          const s16x8 bv = *(const s16x8*)&Vl[(nf * 16 + r) * 72 + ks * 32 + kc * 8];
          acc_o[nf] = mfma16(pa, bv, acc_o[nf]);
        }
      }
      __builtin_amdgcn_s_setprio(0);
    }
  }
#pragma unroll
  for (int j = 0; j < 4; ++j) {
    const float lj = __shfl(l_run, kc * 4 + j);  // l of qrow kc*4+j
    const float inv = 1.0f / lj;
    const size_t orow = (size_t)(b * SQ + qbase + kc * 4 + j) * DIMQ + h * HDQ;
#pragma unroll
    for (int nf = 0; nf < 8; ++nf)
      outb[orow + nf * 16 + r] = f2bf(acc_o[nf][j] * inv);
  }
}

extern "C" void kernel_launch(void* const* d_in, const int* in_sizes, int n_in,
                              void* d_out, int out_size, void* d_ws, size_t ws_size,
                              hipStream_t stream) {
  const float* x   = (const float*)d_in[0];
  const float* wq  = (const float*)d_in[1];
  const float* wk  = (const float*)d_in[2];
  const float* wv  = (const float*)d_in[3];
  const float* wo  = (const float*)d_in[4];
  const float* w1  = (const float*)d_in[5];
  const float* w2  = (const float*)d_in[6];  // note: w2 comes before w3 in dict order
  const float* w3  = (const float*)d_in[7];
  const float* anw = (const float*)d_in[8];
  const float* fnw = (const float*)d_in[9];
  const float* fc  = (const float*)d_in[10];
  const float* fs  = (const float*)d_in[11];
  float* out = (float*)d_out;

  char* ws = (char*)d_ws;
  // weights (bf16, transposed)
  u16* wqkvT = (u16*)(ws);                                  // [6144][2048]
  u16* woT   = (u16*)(ws + 25165824);                       // [2048][2048]
  u16* w13i  = (u16*)(ws + 25165824 + 8388608);             // [11264][2048] interleaved
  u16* w2T   = (u16*)(ws + 25165824 + 8388608 + 46137344);  // [2048][5632]
  // activations
  u16* hin   = (u16*)(ws + 102760448);                      // [4096][2048] bf16
  u16* qkvb  = (u16*)(ws + 119537664);                      // attn: [4096][6144]; FFN: act [4096][5632]
  u16* act   = qkvb;
  u16* attnb = (u16*)(ws + 119537664 + 50331648);           // [4096][2048] bf16
  u16* vtb   = (u16*)(ws + 119537664 + 50331648 + 16777216);// [32][128][2048] bf16
  float* h = out;                                           // h lives in d_out

  const dim3 tb(32, 8);
  transpose_cvt<<<dim3(64, 64), tb, 0, stream>>>(wq, wqkvT, 2048, 2048);
  transpose_cvt<<<dim3(64, 64), tb, 0, stream>>>(wk, wqkvT + (size_t)2048 * 2048, 2048, 2048);
  transpose_cvt<<<dim3(64, 64), tb, 0, stream>>>(wv, wqkvT + (size_t)2 * 2048 * 2048, 2048, 2048);
  transpose_cvt<<<dim3(64, 64), tb, 0, stream>>>(wo, woT, 2048, 2048);
  transpose_cvt_ffn<<<dim3(176, 64), tb, 0, stream>>>(w1, w13i, 0);
  transpose_cvt_ffn<<<dim3(176, 64), tb, 0, stream>>>(w3, w13i, 128);
  transpose_cvt<<<dim3(64, 176), tb, 0, stream>>>(w2, w2T, 5632, 2048);

  rmsnorm_k<<<4096, 256, 0, stream>>>(x, anw, hin);
  gemm256<0, 128, 1><<<768, 512, 0, stream>>>(hin, wqkvT, qkvb, nullptr, nullptr, fc, fs, 6144, 2048, 2048);
  vtrans_k<<<dim3(64, 4, 32), tb, 0, stream>>>(qkvb, vtb);
  attn_k<<<dim3(32, 16), 512, 0, stream>>>(qkvb, vtb, attnb);
  gemm256<1, 128, 0><<<256, 512, 0, stream>>>(attnb, woT, nullptr, h, x, nullptr, nullptr, 2048, 2048, 2048);
  rmsnorm_k<<<4096, 256, 0, stream>>>(h, fnw, hin);
  gemm_ffn<<<704, 512, 0, stream>>>(hin, w13i, act);
  gemm256<1, 128, 0><<<256, 512, 0, stream>>>(act, w2T, nullptr, out, h, nullptr, nullptr, 2048, 5632, 5632);
}

// Round 14
// 575.540 us; speedup vs baseline: 1.1285x; 1.0315x over previous
//
#include <hip/hip_runtime.h>

// ---- problem constants ----
#define DIMQ 2048
#define NHQ  16
#define HDQ  128
#define BQ   2
#define SQ   2048
#define HIDQ 5632
#define MQ   (BQ * SQ)   // 4096
#define SC_ATTN 0.08838834764831845f  // 1/sqrt(128)

using u16 = unsigned short;
using u32 = unsigned int;
typedef __attribute__((ext_vector_type(8))) short s16x8;
typedef __attribute__((ext_vector_type(4))) float f32x4;
typedef __attribute__((ext_vector_type(2))) u32 u32x2;

__device__ __forceinline__ float bf2f(u16 v) {
  union { u32 u; float f; } w; w.u = ((u32)v) << 16; return w.f;
}
__device__ __forceinline__ u16 f2bf(float f) {
  union { float f; u32 u; } w; w.f = f;
  u32 r = w.u + 0x7FFFu + ((w.u >> 16) & 1u);  // RNE
  return (u16)(r >> 16);
}
__device__ __forceinline__ u32 cvtpk_bf16(float a, float b) {
  u32 r;
  asm("v_cvt_pk_bf16_f32 %0, %1, %2" : "=v"(r) : "v"(a), "v"(b));
  return r;
}

__device__ __forceinline__ f32x4 mfma16(s16x8 a, s16x8 b, f32x4 c) {
  return __builtin_amdgcn_mfma_f32_16x16x32_bf16(a, b, c, 0, 0, 0);
}

// async global->LDS, 16B per lane; LDS dest is wave-uniform base + lane*16
__device__ __forceinline__ void gl_lds16(const void* g, void* l) {
  __builtin_amdgcn_global_load_lds((const __attribute__((address_space(1))) void*)g,
                                   (__attribute__((address_space(3))) void*)l,
                                   16, 0, 0);
}

#define SBAR()                                   \
  {                                              \
    asm volatile("" ::: "memory");               \
    __builtin_amdgcn_s_barrier();                \
    asm volatile("" ::: "memory");               \
  }
#define LGKM0() asm volatile("s_waitcnt lgkmcnt(0)" ::: "memory")

// ============================================================================
// Unified weight prep: all 7 f32->bf16 transposes in ONE launch.
// 64x64 tiles; float4 loads (64B/lane), 2x16B bf16 stores (128B/4-lane group).
// Block id ranges select the weight; w1/w3 write the gate/up interleaved w13i.
// ============================================================================
__global__ __launch_bounds__(256) void prep_w(const float* __restrict__ wq,
                                              const float* __restrict__ wk,
                                              const float* __restrict__ wv,
                                              const float* __restrict__ wo,
                                              const float* __restrict__ w1,
                                              const float* __restrict__ w2,
                                              const float* __restrict__ w3,
                                              u16* __restrict__ wqkvT,
                                              u16* __restrict__ woT,
                                              u16* __restrict__ w13i,
                                              u16* __restrict__ w2T) {
  __shared__ float tile[64][68];  // stride 68 f32 = 272B (16B-aligned rows)
  const int id = blockIdx.x;
  const float* src;
  u16* dst;
  int srcStride, dstStride, r0, c0, orow0;
  if (id < 4096) {                       // wq/wk/wv/wo: [2048][2048] plain
    const int w = id >> 10, idd = id & 1023;
    const int tr = idd >> 5, tc = idd & 31;
    src = (w == 0) ? wq : (w == 1) ? wk : (w == 2) ? wv : wo;
    dst = (w == 3) ? woT : wqkvT + (size_t)w * 2048 * 2048;
    srcStride = 2048; dstStride = 2048;
    r0 = tr * 64; c0 = tc * 64; orow0 = c0;
  } else if (id < 9728) {                // w1/w3: [2048][5632] -> w13i interleaved
    const int w = (id - 4096) / 2816;    // 0: w1 (gate), 1: w3 (up)
    const int idd = (id - 4096) % 2816;
    const int tr = idd / 88, tc = idd % 88;
    src = w ? w3 : w1;
    dst = w13i;
    srcStride = 5632; dstStride = 2048;
    r0 = tr * 64; c0 = tc * 64;
    orow0 = ((c0 >> 7) << 8) + (w ? 128 : 0) + (c0 & 127);  // 64-tile never straddles 128
  } else {                               // w2: [5632][2048] plain
    const int idd = id - 9728;
    const int tr = idd / 32, tc = idd % 32;
    src = w2; dst = w2T;
    srcStride = 2048; dstStride = 5632;
    r0 = tr * 64; c0 = tc * 64; orow0 = c0;
  }
  const int t = threadIdx.x;
  const int row = t >> 2, fseg = (t & 3) * 16;
  const float* sp = src + (size_t)(r0 + row) * srcStride + c0 + fseg;
#pragma unroll
  for (int i = 0; i < 4; ++i)
    *(float4*)&tile[row][fseg + i * 4] = *(const float4*)(sp + i * 4);
  __syncthreads();
  const int oc = t >> 2, rs = (t & 3) * 16;
  u16 outv[16];
#pragma unroll
  for (int i = 0; i < 16; ++i) outv[i] = f2bf(tile[rs + i][oc]);
  u16* dp = dst + (size_t)(orow0 + oc) * dstStride + r0 + rs;
  *(s16x8*)dp = *(const s16x8*)&outv[0];
  *(s16x8*)(dp + 8) = *(const s16x8*)&outv[8];
}

// ---- V transpose: qkv v-slice [s][d] bf16 -> Vt[bh][d][s] bf16 ----
__global__ __launch_bounds__(256) void vtrans_k(const u16* __restrict__ qkv,
                                                u16* __restrict__ vt) {
  __shared__ u16 tile[32][33];
  const int bh = blockIdx.z;
  const int b = bh >> 4, h = bh & 15;
  const int s0 = blockIdx.x * 32, d0 = blockIdx.y * 32;
  const int tx = threadIdx.x, ty = threadIdx.y;
  const u16* src = qkv + (size_t)(b * SQ) * 6144 + 4096 + h * HDQ;
#pragma unroll
  for (int i = 0; i < 4; ++i)
    tile[ty + i * 8][tx] = src[(size_t)(s0 + ty + i * 8) * 6144 + d0 + tx];
  __syncthreads();
  u16* dst = vt + (size_t)bh * HDQ * SQ;
#pragma unroll
  for (int i = 0; i < 4; ++i)
    dst[(size_t)(d0 + ty + i * 8) * SQ + s0 + tx] = tile[tx][ty + i * 8];
}

// ---- RMSNorm: f32 [rows][2048] -> bf16, one block per row ----
__global__ __launch_bounds__(256) void rmsnorm_k(const float* __restrict__ x,
                                                 const float* __restrict__ w,
                                                 u16* __restrict__ o) {
  const int row = blockIdx.x;
  const int t = threadIdx.x;
  const float* xr = x + (size_t)row * DIMQ;
  const float4 a = ((const float4*)xr)[t * 2];
  const float4 b = ((const float4*)xr)[t * 2 + 1];
  float ss = a.x * a.x + a.y * a.y + a.z * a.z + a.w * a.w +
             b.x * b.x + b.y * b.y + b.z * b.z + b.w * b.w;
#pragma unroll
  for (int off = 32; off > 0; off >>= 1) ss += __shfl_down(ss, off);
  __shared__ float red[4];
  if ((t & 63) == 0) red[t >> 6] = ss;
  __syncthreads();
  ss = red[0] + red[1] + red[2] + red[3];
  const float rs = rsqrtf(ss * (1.0f / (float)DIMQ) + 1e-6f);
  const float4 wa = ((const float4*)w)[t * 2];
  const float4 wb = ((const float4*)w)[t * 2 + 1];
  s16x8 ov;
  ov[0] = (short)f2bf(a.x * rs * wa.x);
  ov[1] = (short)f2bf(a.y * rs * wa.y);
  ov[2] = (short)f2bf(a.z * rs * wa.z);
  ov[3] = (short)f2bf(a.w * rs * wa.w);
  ov[4] = (short)f2bf(b.x * rs * wb.x);
  ov[5] = (short)f2bf(b.y * rs * wb.y);
  ov[6] = (short)f2bf(b.z * rs * wb.z);
  ov[7] = (short)f2bf(b.w * rs * wb.w);
  *(s16x8*)(o + (size_t)row * DIMQ + t * 8) = ov;
}

// ============================================================================
// 256xBN tile GEMM, BK=64, 8 waves, round-6 free-form 4-phase body (633us
// baseline): B(t+1) staged ph0/ph1, A(t+2) staged ph3, counted vmcnt(4).
// ============================================================================
template <int OM, int BN, int ROPE>
__global__ __launch_bounds__(512, 1) void gemm256(const u16* __restrict__ A,
                                                  const u16* __restrict__ Bt,
                                                  u16* __restrict__ Cb,
                                                  float* __restrict__ Cf,
                                                  const float* __restrict__ resid,
                                                  const float* __restrict__ fc,
                                                  const float* __restrict__ fs,
                                                  int N, int K, int lda) {
  constexpr int BT = BN * 128;             // B K-tile bytes
  constexpr int BLB = BN / 128;            // gl_lds per thread per B half
  constexpr int WNv = (BN == 256) ? 4 : 2; // waves along N
  constexpr int MF = (BN == 256) ? 8 : 4;  // 16-row A frags per wave
  constexpr int MFH = MF / 2;
  __shared__ u16 lds[(65536 + 2 * BT) / 2];  // A: 0,32768; B: 65536, 65536+BT
  const int tid = threadIdx.x, wid = tid >> 6, lane = tid & 63;
  const int wm = wid / WNv, wn = wid % WNv;
  const int r = lane & 15, kc = lane >> 4;
  const int nbx = N / BN;
  const int nwg = nbx << 4;
  const int o = blockIdx.x;
  const int seq = (o & 7) * (nwg >> 3) + (o >> 3);  // XCD-chunked, row-major
  const int by = seq / nbx, bx = seq - by * nbx;
  const int m0 = by << 8, n0 = bx * BN;
  const int T = K >> 6;

  const u16* Ag = A + (size_t)m0 * lda;
  const u16* Bg = Bt + (size_t)n0 * K;

  // staging source swizzle (involution byte^=((byte>>7&7)<<4); linear LDS dest)
  const int pl = (tid * 16) ^ (((tid >> 3) & 7) << 4);
  const int prow = pl >> 7;           // = tid>>3, 0..63
  const int pcol = (pl & 127) >> 1;   // element offset within 64-elem row

  // read-side swizzled base: row r, k-chunk kc (XOR ks<<6 per k-slice)
  const int rd0 = r * 128 + ((kc * 16) ^ ((r & 7) << 4));
  const int waveA = wm * (MF * 2048);
  const int waveB = wn * 8192;

  f32x4 acc[MF][4] = {};
  s16x8 af[MFH][2], bfL[2][2], bfH[2][2];

#define STAGE_A(G, kt, BUFB, h)                                                   \
  {                                                                               \
    _Pragma("unroll") for (int i = 0; i < 2; ++i)                                 \
        gl_lds16(G + (size_t)((h) * 128 + i * 64 + prow) * lda + (kt) * 64 + pcol,\
                 (char*)lds + (BUFB) + (h) * 16384 + i * 8192 + (wid << 10));     \
  }
#define STAGE_B(G, kt, BUFB, h)                                                   \
  {                                                                               \
    _Pragma("unroll") for (int i = 0; i < BLB; ++i)                               \
        gl_lds16(G + (size_t)((h) * (BN / 2) + i * 64 + prow) * K + (kt) * 64 + pcol, \
                 (char*)lds + (BUFB) + (h) * (BT / 2) + i * 8192 + (wid << 10));  \
  }

  // prologue: tile0 A+B -> buf0; tile1 A -> buf1
  STAGE_A(Ag, 0, 0, 0);
  STAGE_A(Ag, 0, 0, 1);
  STAGE_B(Bg, 0, 65536, 0);
  STAGE_B(Bg, 0, 65536, 1);
  STAGE_A(Ag, 1, 32768, 0);
  STAGE_A(Ag, 1, 32768, 1);
  asm volatile("s_waitcnt vmcnt(4)" ::: "memory");
  SBAR();

#define TILE_BODY(t, cur)                                                         \
  {                                                                               \
    const int tp1 = ((t) + 1 < T) ? (t) + 1 : T - 1;                              \
    const int tp2 = ((t) + 2 < T) ? (t) + 2 : T - 1;                              \
    const int AB = (cur)*32768;                                                   \
    const int BB = 65536 + (cur)*BT;                                              \
    const int BBn = 65536 + (1 - (cur)) * BT;                                     \
    /* ---- phase 0: stage B.h0(t+1); read A(lo)+B(lo); mfma Q(0,0) ---- */       \
    STAGE_B(Bg, tp1, BBn, 0);                                                     \
    _Pragma("unroll") for (int j = 0; j < MFH; ++j)                               \
        _Pragma("unroll") for (int ks = 0; ks < 2; ++ks)                          \
            af[j][ks] = *(const s16x8*)((const char*)lds + AB + waveA +           \
                                        j * 2048 + (rd0 ^ (ks << 6)));            \
    _Pragma("unroll") for (int n = 0; n < 2; ++n)                                 \
        _Pragma("unroll") for (int ks = 0; ks < 2; ++ks)                          \
            bfL[n][ks] = *(const s16x8*)((const char*)lds + BB + waveB +          \
                                         n * 2048 + (rd0 ^ (ks << 6)));           \
    __builtin_amdgcn_s_setprio(1);                                                \
    _Pragma("unroll") for (int ks = 0; ks < 2; ++ks)                              \
        _Pragma("unroll") for (int j = 0; j < MFH; ++j)                           \
            _Pragma("unroll") for (int n = 0; n < 2; ++n)                         \
                acc[j][n] = mfma16(af[j][ks], bfL[n][ks], acc[j][n]);             \
    __builtin_amdgcn_s_setprio(0);                                                \
    /* ---- phase 1: stage B.h1(t+1); read B(hi); mfma Q(0,1) ---- */             \
    STAGE_B(Bg, tp1, BBn, 1);                                                     \
    _Pragma("unroll") for (int n = 0; n < 2; ++n)                                 \
        _Pragma("unroll") for (int ks = 0; ks < 2; ++ks)                          \
            bfH[n][ks] = *(const s16x8*)((const char*)lds + BB + waveB +          \
                                         (2 + n) * 2048 + (rd0 ^ (ks << 6)));     \
    __builtin_amdgcn_s_setprio(1);                                                \
    _Pragma("unroll") for (int ks = 0; ks < 2; ++ks)                              \
        _Pragma("unroll") for (int j = 0; j < MFH; ++j)                           \
            _Pragma("unroll") for (int n = 0; n < 2; ++n)                         \
                acc[j][2 + n] = mfma16(af[j][ks], bfH[n][ks], acc[j][2 + n]);     \
    __builtin_amdgcn_s_setprio(0);                                                \
    /* ---- phase 2: read A(hi); mfma Q(1,0) ---- */                              \
    _Pragma("unroll") for (int j = 0; j < MFH; ++j)                               \
        _Pragma("unroll") for (int ks = 0; ks < 2; ++ks)                          \
            af[j][ks] = *(const s16x8*)((const char*)lds + AB + waveA +           \
                                        (MFH + j) * 2048 + (rd0 ^ (ks << 6)));    \
    __builtin_amdgcn_s_setprio(1);                                                \
    _Pragma("unroll") for (int ks = 0; ks < 2; ++ks)                              \
        _Pragma("unroll") for (int j = 0; j < MFH; ++j)                           \
            _Pragma("unroll") for (int n = 0; n < 2; ++n)                         \
                acc[MFH + j][n] = mfma16(af[j][ks], bfL[n][ks], acc[MFH + j][n]); \
    __builtin_amdgcn_s_setprio(0);                                                \
    SBAR(); /* all reads of buf[cur] done -> safe to overwrite its A region */    \
    /* ---- phase 3: stage A(t+2) into buf[cur]; mfma Q(1,1) ---- */              \
    STAGE_A(Ag, tp2, AB, 0);                                                      \
    STAGE_A(Ag, tp2, AB, 1);                                                      \
    __builtin_amdgcn_s_setprio(1);                                                \
    _Pragma("unroll") for (int ks = 0; ks < 2; ++ks)                              \
        _Pragma("unroll") for (int j = 0; j < MFH; ++j)                           \
            _Pragma("unroll") for (int n = 0; n < 2; ++n)                         \
                acc[MFH + j][2 + n] = mfma16(af[j][ks], bfH[n][ks], acc[MFH + j][2 + n]); \
    __builtin_amdgcn_s_setprio(0);                                                \
    asm volatile("s_waitcnt vmcnt(4)" ::: "memory"); /* A(t+1)+B(t+1) landed */   \
    SBAR();                                                                       \
  }

  for (int tt = 0; tt < T; tt += 2) {  // T even for all shapes (32, 88)
    TILE_BODY(tt, 0);
    TILE_BODY(tt + 1, 1);
  }
#undef TILE_BODY
#undef STAGE_A
#undef STAGE_B

  const bool do_rope = ROPE && (n0 < 4096);
#pragma unroll
  for (int mf = 0; mf < MF; ++mf)
#pragma unroll
    for (int nf = 0; nf < 4; ++nf)
#pragma unroll
      for (int j = 0; j < 4; ++j) {
        const int rr = m0 + wm * (MF * 16) + mf * 16 + kc * 4 + j;
        const int cc = n0 + wn * 64 + nf * 16 + r;
        float v = acc[mf][nf][j];
        if (OM == 0) {
          if (ROPE) {  // fused RoPE: lanes r, r^1 hold (re,im) of one pair
            const float partner = __shfl_xor(v, 1);
            if (do_rope) {
              const int s = rr & (SQ - 1);
              const int i0 = (cc >> 1) & 63;
              const float cv = fc[s * 64 + i0];
              const float sv = fs[s * 64 + i0];
              v = ((r & 1) == 0) ? v * cv - partner * sv : v * cv + partner * sv;
            }
          }
          Cb[(size_t)rr * N + cc] = f2bf(v);
        } else {
          Cf[(size_t)rr * N + cc] = v + resid[(size_t)rr * N + cc];
        }
      }
}

// ============================================================================
// Fused FFN GEMM (round-6 free-form body): act = silu(f_in@w1)*(f_in@w3).
// ============================================================================
__global__ __launch_bounds__(512, 1) void gemm_ffn(const u16* __restrict__ A,
                                                   const u16* __restrict__ Bi,
                                                   u16* __restrict__ act) {
  __shared__ u16 lds[65536];  // A bufs @0,32768; B bufs @65536,98304 (bytes)
  const int tid = threadIdx.x, wid = tid >> 6, lane = tid & 63;
  const int wm = wid >> 1, wn = wid & 1;
  const int r = lane & 15, kc = lane >> 4;
  const int o = blockIdx.x;                 // 704 blocks = 16 m x 44 chunks
  const int seq = (o & 7) * 88 + (o >> 3);  // XCD-chunked, row-major
  const int by = seq / 44, bx = seq - by * 44;
  const int m0 = by << 8;
  const int T = 32;  // K = 2048

  const u16* Ag = A + (size_t)m0 * DIMQ;
  const u16* Bg = Bi + (size_t)bx * 256 * DIMQ;

  const int pl = (tid * 16) ^ (((tid >> 3) & 7) << 4);
  const int prow = pl >> 7, pcol = (pl & 127) >> 1;
  const int rd0 = r * 128 + ((kc * 16) ^ ((r & 7) << 4));
  const int waveA = wm * 8192;  // 64 rows
  const int waveB = wn * 8192;  // 64 gate rows (up at +16384)

  f32x4 accG[4][4] = {}, accU[4][4] = {};
  s16x8 af[4][2], bL[2][2], bH[2][2];

#define STG(G, kt, BUFB, h)                                                       \
  {                                                                               \
    _Pragma("unroll") for (int i = 0; i < 2; ++i)                                 \
        gl_lds16(G + (size_t)((h) * 128 + i * 64 + prow) * DIMQ + (kt) * 64 + pcol,\
                 (char*)lds + (BUFB) + (h) * 16384 + i * 8192 + (wid << 10));     \
  }

  STG(Ag, 0, 0, 0);
  STG(Ag, 0, 0, 1);
  STG(Bg, 0, 65536, 0);
  STG(Bg, 0, 65536, 1);
  STG(Ag, 1, 32768, 0);
  STG(Ag, 1, 32768, 1);
  asm volatile("s_waitcnt vmcnt(4)" ::: "memory");
  SBAR();

#define FFN_BODY(t, cur)                                                          \
  {                                                                               \
    const int tp1 = ((t) + 1 < T) ? (t) + 1 : T - 1;                              \
    const int tp2 = ((t) + 2 < T) ? (t) + 2 : T - 1;                              \
    const int AB = (cur)*32768;                                                   \
    const int BB = 65536 + (cur)*32768;                                           \
    const int BBn = 65536 + (1 - (cur)) * 32768;                                  \
    /* ph0: stage B.h0(t+1); read af + gate01; mfma G01 */                        \
    STG(Bg, tp1, BBn, 0);                                                         \
    _Pragma("unroll") for (int j = 0; j < 4; ++j)                                 \
        _Pragma("unroll") for (int ks = 0; ks < 2; ++ks)                          \
            af[j][ks] = *(const s16x8*)((const char*)lds + AB + waveA +           \
                                        j * 2048 + (rd0 ^ (ks << 6)));            \
    _Pragma("unroll") for (int n = 0; n < 2; ++n)                                 \
        _Pragma("unroll") for (int ks = 0; ks < 2; ++ks)                          \
            bL[n][ks] = *(const s16x8*)((const char*)lds + BB + waveB +           \
                                        n * 2048 + (rd0 ^ (ks << 6)));            \
    __builtin_amdgcn_s_setprio(1);                                                \
    _Pragma("unroll") for (int ks = 0; ks < 2; ++ks)                              \
        _Pragma("unroll") for (int j = 0; j < 4; ++j)                             \
            _Pragma("unroll") for (int n = 0; n < 2; ++n)                         \
                accG[j][n] = mfma16(af[j][ks], bL[n][ks], accG[j][n]);            \
    __builtin_amdgcn_s_setprio(0);                                                \
    /* ph1: stage B.h1(t+1); read gate23; mfma G23 */                             \
    STG(Bg, tp1, BBn, 1);                                                         \
    _Pragma("unroll") for (int n = 0; n < 2; ++n)                                 \
        _Pragma("unroll") for (int ks = 0; ks < 2; ++ks)                          \
            bH[n][ks] = *(const s16x8*)((const char*)lds + BB + waveB +           \
                                        (2 + n) * 2048 + (rd0 ^ (ks << 6)));      \
    __builtin_amdgcn_s_setprio(1);                                                \
    _Pragma("unroll") for (int ks = 0; ks < 2; ++ks)                              \
        _Pragma("unroll") for (int j = 0; j < 4; ++j)                             \
            _Pragma("unroll") for (int n = 0; n < 2; ++n)                         \
                accG[j][2 + n] = mfma16(af[j][ks], bH[n][ks], accG[j][2 + n]);    \
    __builtin_amdgcn_s_setprio(0);                                                \
    /* ph2: read up01; mfma U01 */                                                \
    _Pragma("unroll") for (int n = 0; n < 2; ++n)                                 \
        _Pragma("unroll") for (int ks = 0; ks < 2; ++ks)                          \
            bL[n][ks] = *(const s16x8*)((const char*)lds + BB + 16384 + waveB +   \
                                        n * 2048 + (rd0 ^ (ks << 6)));            \
    __builtin_amdgcn_s_setprio(1);                                                \
    _Pragma("unroll") for (int ks = 0; ks < 2; ++ks)                              \
        _Pragma("unroll") for (int j = 0; j < 4; ++j)                             \
            _Pragma("unroll") for (int n = 0; n < 2; ++n)                         \
                accU[j][n] = mfma16(af[j][ks], bL[n][ks], accU[j][n]);            \
    __builtin_amdgcn_s_setprio(0);                                                \
    /* ph2b: read up23 (B-buf: not touched by STAGE_A, may cross barrier) */      \
    _Pragma("unroll") for (int n = 0; n < 2; ++n)                                 \
        _Pragma("unroll") for (int ks = 0; ks < 2; ++ks)                          \
            bH[n][ks] = *(const s16x8*)((const char*)lds + BB + 16384 + waveB +   \
                                        (2 + n) * 2048 + (rd0 ^ (ks << 6)));      \
    SBAR(); /* all A-buf reads done -> safe to overwrite */                       \
    /* ph3: stage A(t+2); mfma U23 */                                             \
    STG(Ag, tp2, AB, 0);                                                          \
    STG(Ag, tp2, AB, 1);                                                          \
    __builtin_amdgcn_s_setprio(1);                                                \
    _Pragma("unroll") for (int ks = 0; ks < 2; ++ks)                              \
        _Pragma("unroll") for (int j = 0; j < 4; ++j)                             \
            _Pragma("unroll") for (int n = 0; n < 2; ++n)                         \
                accU[j][2 + n] = mfma16(af[j][ks], bH[n][ks], accU[j][2 + n]);    \
    __builtin_amdgcn_s_setprio(0);                                                \
    asm volatile("s_waitcnt vmcnt(4)" ::: "memory");                              \
    SBAR();                                                                       \
  }

  for (int tt = 0; tt < T; tt += 2) {
    FFN_BODY(tt, 0);
    FFN_BODY(tt + 1, 1);
  }
#undef FFN_BODY
#undef STG

  const int cbase = bx * 128 + wn * 64;
#pragma unroll
  for (int mf = 0; mf < 4; ++mf)
#pragma unroll
    for (int nf = 0; nf < 4; ++nf)
#pragma unroll
      for (int j = 0; j < 4; ++j) {
        const int rr = m0 + wm * 64 + mf * 16 + kc * 4 + j;
        const int cc = cbase + nf * 16 + r;
        const float g = accG[mf][nf][j];
        const float u = accU[mf][nf][j];
        const float a = g / (1.f + __expf(-g)) * u;
        act[(size_t)rr * HIDQ + cc] = f2bf(a);
      }
}

// ============================================================================
// Causal flash attention, diagonal-paired; SWAPPED QK^T softmax:
// st = mfma(K, Q) puts S[qrow=lane&15][16 keys] lane-local -> row reduce is
// 15 serial ops + 2 shfl_xor(16,32). Defer-max (THR=8, log2 domain), exp2
// with SC*log2e folded into Q, cvt_pk_bf16 P-packing (4x 8B LDS writes).
// ============================================================================
__global__ __launch_bounds__(512) void attn_k(const u16* __restrict__ qkv,
                                              const u16* __restrict__ vt,
                                              u16* __restrict__ outb) {
  __shared__ u16 Kl[64 * 136];      // [key][d], stride 136
  __shared__ u16 Vl[128 * 72];      // [d][key], stride 72
  __shared__ u16 Pl[8][16 * 80];    // per-wave P tile [qrow][key]
  const int bh = blockIdx.x;
  const int pr = blockIdx.y;         // 0..15
  const int b = bh >> 4, h = bh & 15;
  const int tid = threadIdx.x, wid = tid >> 6, lane = tid & 63;
  const int r = lane & 15, kc = lane >> 4;
  const int nt_lo = pr + 1, nt = 32 - pr;
  const int qbase = ((wid < 4) ? pr * 64 : (31 - pr) * 64) + (wid & 3) * 16;
  const int qrow_r = qbase + r;      // this lane's softmax q-row
  const size_t base = (size_t)b * SQ * 6144;
  const u16* vtb = vt + (size_t)bh * HDQ * SQ;
  s16x8 qf[4];
  {
    const size_t qoff = base + (size_t)qrow_r * 6144 + h * HDQ;
    const float QSC = SC_ATTN * 1.44269504f;  // fold 1/sqrt(d) * log2(e)
#pragma unroll
    for (int kk = 0; kk < 4; ++kk) {
      s16x8 v = *(const s16x8*)&qkv[qoff + kk * 32 + kc * 8];
#pragma unroll
      for (int e = 0; e < 8; ++e) v[e] = (short)f2bf(bf2f((u16)v[e]) * QSC);
      qf[kk] = v;
    }
  }
  f32x4 acc_o[8] = {};
  float m_run = -1e30f, l_run = 0.f;
  // staging indices (512 threads)
  const int kr = tid >> 4, kc8 = (tid & 15) * 8;   // K: rows kr, kr+32; 128 elems
  const int vr = tid >> 3, vc8 = (tid & 7) * 8;    // V: rows vr, vr+64; 64 elems
  const u16* kgp = &qkv[base + (size_t)kr * 6144 + 2048 + h * HDQ + kc8];
  const u16* vgp = &vtb[(size_t)vr * SQ + vc8];
  s16x8 kreg[2], vreg[2];
  kreg[0] = *(const s16x8*)kgp;
  kreg[1] = *(const s16x8*)(kgp + (size_t)32 * 6144);
  vreg[0] = *(const s16x8*)vgp;
  vreg[1] = *(const s16x8*)(vgp + (size_t)64 * SQ);
  for (int t = 0; t < nt; ++t) {
    const int kv0 = t * 64;
    __syncthreads();  // previous tile's LDS reads done
    *(s16x8*)&Kl[kr * 136 + kc8] = kreg[0];
    *(s16x8*)&Kl[(kr + 32) * 136 + kc8] = kreg[1];
    *(s16x8*)&Vl[vr * 72 + vc8] = vreg[0];
    *(s16x8*)&Vl[(vr + 64) * 72 + vc8] = vreg[1];
    __syncthreads();
    if (t + 1 < nt) {  // issue next tile's loads; land under compute (T14)
      const u16* kg = kgp + (size_t)(kv0 + 64) * 6144;
      const u16* vg = vgp + (kv0 + 64);
      kreg[0] = *(const s16x8*)kg;
      kreg[1] = *(const s16x8*)(kg + (size_t)32 * 6144);
      vreg[0] = *(const s16x8*)vg;
      vreg[1] = *(const s16x8*)(vg + (size_t)64 * SQ);
    }
    if (wid >= 4 || t < nt_lo) {
      // S^T = K*Q^T: lane (r,kc) holds S[qrow=r][key = kv0 + nf*16 + kc*4 + j]
      f32x4 st[4] = {};
      __builtin_amdgcn_s_setprio(1);
#pragma unroll
      for (int nf = 0; nf < 4; ++nf)
#pragma unroll
        for (int kk = 0; kk < 4; ++kk) {
          const s16x8 kf = *(const s16x8*)&Kl[(nf * 16 + r) * 136 + kk * 32 + kc * 8];
          st[nf] = mfma16(kf, qf[kk], st[nf]);
        }
      __builtin_amdgcn_s_setprio(0);
      // masked per-lane max over this lane's 16 keys, then merge across kc
      float pv[16];
      float tm = -1e30f;
#pragma unroll
      for (int nf = 0; nf < 4; ++nf)
#pragma unroll
        for (int j = 0; j < 4; ++j) {
          const int key = kv0 + nf * 16 + kc * 4 + j;
          float sv = st[nf][j];
          sv = (key > qrow_r) ? -1e30f : sv;
          pv[nf * 4 + j] = sv;
          tm = fmaxf(tm, sv);
        }
      tm = fmaxf(tm, __shfl_xor(tm, 16));
      tm = fmaxf(tm, __shfl_xor(tm, 32));
      // defer-max: rescale only if some row's max grew past THR=8 (log2 units)
      if (__any(tm > m_run + 8.f)) {
        const float mnew = fmaxf(m_run, tm);
        const float alpha = exp2f(m_run - mnew);
        m_run = mnew;
        l_run *= alpha;
#pragma unroll
        for (int j = 0; j < 4; ++j) {
          const float aj = __shfl(alpha, kc * 4 + j);  // alpha of qrow kc*4+j
#pragma unroll
          for (int nf = 0; nf < 8; ++nf) acc_o[nf][j] *= aj;
        }
      }
      float rs = 0.f;
      u32 pk0[4], pk1[4];
#pragma unroll
      for (int nf = 0; nf < 4; ++nf) {
        const float p0 = exp2f(pv[nf * 4 + 0] - m_run);
        const float p1 = exp2f(pv[nf * 4 + 1] - m_run);
        const float p2 = exp2f(pv[nf * 4 + 2] - m_run);
        const float p3 = exp2f(pv[nf * 4 + 3] - m_run);
        rs += (p0 + p1) + (p2 + p3);
        pk0[nf] = cvtpk_bf16(p0, p1);
        pk1[nf] = cvtpk_bf16(p2, p3);
      }
      rs += __shfl_xor(rs, 16);
      rs += __shfl_xor(rs, 32);
      l_run += rs;
      // write P: lane (r,kc) owns keys nf*16 + kc*4 + [0,4) of row r
#pragma unroll
      for (int nf = 0; nf < 4; ++nf) {
        u32x2 w;
        w[0] = pk0[nf];
        w[1] = pk1[nf];
        *(u32x2*)&Pl[wid][r * 80 + nf * 16 + kc * 4] = w;
      }
      __builtin_amdgcn_s_setprio(1);
#pragma unroll
      for (int ks = 0; ks < 2; ++ks) {
        const s16x8 pa = *(const s16x8*)&Pl[wid][r * 80 + ks * 32 + kc * 8];
#pragma unroll
        for (int nf = 0; nf < 8; ++nf) {
          const s16x8 bv = *(const s16x8*)&Vl[(nf * 16 + r) * 72 + ks * 32 + kc * 8];
          acc_o[nf] = mfma16(pa, bv, acc_o[nf]);
        }
      }
      __builtin_amdgcn_s_setprio(0);
    }
  }
#pragma unroll
  for (int j = 0; j < 4; ++j) {
    const float lj = __shfl(l_run, kc * 4 + j);  // l of qrow kc*4+j
    const float inv = 1.0f / lj;
    const size_t orow = (size_t)(b * SQ + qbase + kc * 4 + j) * DIMQ + h * HDQ;
#pragma unroll
    for (int nf = 0; nf < 8; ++nf)
      outb[orow + nf * 16 + r] = f2bf(acc_o[nf][j] * inv);
  }
}

extern "C" void kernel_launch(void* const* d_in, const int* in_sizes, int n_in,
                              void* d_out, int out_size, void* d_ws, size_t ws_size,
                              hipStream_t stream) {
  const float* x   = (const float*)d_in[0];
  const float* wq  = (const float*)d_in[1];
  const float* wk  = (const float*)d_in[2];
  const float* wv  = (const float*)d_in[3];
  const float* wo  = (const float*)d_in[4];
  const float* w1  = (const float*)d_in[5];
  const float* w2  = (const float*)d_in[6];  // note: w2 comes before w3 in dict order
  const float* w3  = (const float*)d_in[7];
  const float* anw = (const float*)d_in[8];
  const float* fnw = (const float*)d_in[9];
  const float* fc  = (const float*)d_in[10];
  const float* fs  = (const float*)d_in[11];
  float* out = (float*)d_out;

  char* ws = (char*)d_ws;
  // weights (bf16, transposed)
  u16* wqkvT = (u16*)(ws);                                  // [6144][2048]
  u16* woT   = (u16*)(ws + 25165824);                       // [2048][2048]
  u16* w13i  = (u16*)(ws + 25165824 + 8388608);             // [11264][2048] interleaved
  u16* w2T   = (u16*)(ws + 25165824 + 8388608 + 46137344);  // [2048][5632]
  // activations
  u16* hin   = (u16*)(ws + 102760448);                      // [4096][2048] bf16
  u16* qkvb  = (u16*)(ws + 119537664);                      // attn: [4096][6144]; FFN: act [4096][5632]
  u16* act   = qkvb;
  u16* attnb = (u16*)(ws + 119537664 + 50331648);           // [4096][2048] bf16
  u16* vtb   = (u16*)(ws + 119537664 + 50331648 + 16777216);// [32][128][2048] bf16
  float* h = out;                                           // h lives in d_out

  const dim3 tb(32, 8);
  prep_w<<<12544, 256, 0, stream>>>(wq, wk, wv, wo, w1, w2, w3, wqkvT, woT, w13i, w2T);

  rmsnorm_k<<<4096, 256, 0, stream>>>(x, anw, hin);
  gemm256<0, 128, 1><<<768, 512, 0, stream>>>(hin, wqkvT, qkvb, nullptr, nullptr, fc, fs, 6144, 2048, 2048);
  vtrans_k<<<dim3(64, 4, 32), tb, 0, stream>>>(qkvb, vtb);
  attn_k<<<dim3(32, 16), 512, 0, stream>>>(qkvb, vtb, attnb);
  gemm256<1, 128, 0><<<256, 512, 0, stream>>>(attnb, woT, nullptr, h, x, nullptr, nullptr, 2048, 2048, 2048);
  rmsnorm_k<<<4096, 256, 0, stream>>>(h, fnw, hin);
  gemm_ffn<<<704, 512, 0, stream>>>(hin, w13i, act);
  gemm256<1, 128, 0><<<256, 512, 0, stream>>>(act, w2T, nullptr, out, h, nullptr, nullptr, 2048, 5632, 5632);
}